// Round 8
// baseline (341.452 us; speedup 1.0000x reference)
//
#include <hip/hip_runtime.h>
#include <math.h>

#define GAMMA 0.1f

typedef float f32x4 __attribute__((ext_vector_type(4)));
typedef short short8 __attribute__((ext_vector_type(8)));

static __device__ __forceinline__ unsigned short f2bf(float f) {
  union { float f; unsigned u; } v; v.f = f;
  unsigned r = v.u + 0x7FFF + ((v.u >> 16) & 1);   // RNE
  return (unsigned short)(r >> 16);
}
static __device__ __forceinline__ float bf2f(unsigned short b) {
  union { unsigned u; float f; } v; v.u = ((unsigned)b) << 16;
  return v.f;
}

// ---------------------------------------------------------------------------
// Build transposed bf16 B matrix: Bt[c][k], c in [0,COLS), k in [0,KPAD)
//   c < H : W[k][c];  c == H : sc[k];  c == H+1 : dk[k];  else/k>=Kact : 0
// ---------------------------------------------------------------------------
__global__ __launch_bounds__(256) void build_bt(
    const float* __restrict__ W, const float* __restrict__ sc,
    const float* __restrict__ dk, unsigned short* __restrict__ Bt,
    int H, int Kact, int KPAD, int COLS) {
  int i = blockIdx.x * 256 + threadIdx.x;
  if (i >= COLS * KPAD) return;
  int c = i / KPAD;
  int k = i - c * KPAD;
  float v = 0.f;
  if (k < Kact) {
    if (c < H) v = W[(size_t)k * H + c];
    else if (c == H) v = sc[k];
    else if (c == H + 1) v = dk[k];
  }
  Bt[i] = f2bf(v);
}

// ---------------------------------------------------------------------------
// Fused MFMA linear: out = A @ W (bf16 out), s = sigmoid(A@sc+sb), Dk = A@dk+db
// OSPLIT: write output as two N x (H/2) halves (L2-resident gather feed).
// ABF: A is bf16 stored as split halves (lo: cols 0-31, hi: 32-63), KPAD==64.
// ---------------------------------------------------------------------------
template <int KPAD, int CFRAGS, int OUTFRAGS, bool ABF, bool OSPLIT>
__global__ __launch_bounds__(256) void mfma_linear(
    const void* __restrict__ Alo, const void* __restrict__ Ahi,
    const unsigned short* __restrict__ Bt,
    const float* __restrict__ sb, const float* __restrict__ db,
    unsigned short* __restrict__ outLo, unsigned short* __restrict__ outHi,
    float* __restrict__ s, float* __restrict__ Dk, int N, int Kact) {
  const int w = threadIdx.x >> 6;
  const int l = threadIdx.x & 63;
  const int kgrp = l >> 4;          // 0..3
  const int lc = l & 15;
  const int rowA = blockIdx.x * 64 + w * 16 + lc;       // A-fragment row
  const int rowD = blockIdx.x * 64 + w * 16 + kgrp * 4; // D rows base

  f32x4 acc[CFRAGS];
#pragma unroll
  for (int i = 0; i < CFRAGS; ++i) acc[i] = (f32x4)0.f;

#pragma unroll
  for (int ks = 0; ks < KPAD / 32; ++ks) {
    const int kb = ks * 32 + kgrp * 8;
    short8 av;
    if (rowA < N) {
      if (ABF) {
        // split bf16 A: kb<32 -> lo half, else hi half (kb&31 = kgrp*8)
        const unsigned short* Ab =
            (kb < 32) ? (const unsigned short*)Alo : (const unsigned short*)Ahi;
        av = *(const short8*)(Ab + (size_t)rowA * 32 + (kb & 31));
      } else {
        const float* A = (const float*)Alo + (size_t)rowA * Kact;
        if (kb + 8 <= Kact) {
          f32x4 f0 = *(const f32x4*)(A + kb);
          f32x4 f1 = *(const f32x4*)(A + kb + 4);
#pragma unroll
          for (int j = 0; j < 4; ++j) {
            av[j] = (short)f2bf(f0[j]);
            av[j + 4] = (short)f2bf(f1[j]);
          }
        } else {
#pragma unroll
          for (int j = 0; j < 8; ++j) {
            int f = kb + j;
            av[j] = (short)f2bf(f < Kact ? A[f] : 0.f);
          }
        }
      }
    } else {
#pragma unroll
      for (int j = 0; j < 8; ++j) av[j] = 0;
    }

#pragma unroll
    for (int fc = 0; fc < CFRAGS; ++fc) {
      short8 bv = *(const short8*)(Bt + (size_t)(fc * 16 + lc) * KPAD + kb);
      acc[fc] = __builtin_amdgcn_mfma_f32_16x16x32_bf16(av, bv, acc[fc], 0, 0, 0);
    }
  }

  // epilogue: xW (bf16), optionally split into lo/hi halves
#pragma unroll
  for (int fc = 0; fc < OUTFRAGS; ++fc) {
    constexpr int HALF = OSPLIT ? (OUTFRAGS / 2) * 16 : OUTFRAGS * 16;
    unsigned short* ob =
        OSPLIT ? ((fc < OUTFRAGS / 2) ? outLo : outHi) : outLo;
    const int col = OSPLIT ? (fc % (OUTFRAGS / 2 ? OUTFRAGS / 2 : 1)) * 16 + lc
                           : fc * 16 + lc;
#pragma unroll
    for (int r = 0; r < 4; ++r) {
      int gr = rowD + r;
      if (gr < N) ob[(size_t)gr * HALF + col] = f2bf(acc[fc][r]);
    }
  }
  // gate + degree columns live in the last fragment (local cols 0 and 1)
  if (lc < 2) {
    f32x4 g = acc[CFRAGS - 1];
#pragma unroll
    for (int r = 0; r < 4; ++r) {
      int gr = rowD + r;
      if (gr < N) {
        if (lc == 0) s[gr] = 1.f / (1.f + expf(-(g[r] + sb[0])));
        else Dk[gr] = g[r] + db[0];
      }
    }
  }
}

// ---------------------------------------------------------------------------
// Tile binning: bucket = dst >> 7 (128-node tiles). nb <= 512 assumed.
// All histogram/cursor atomics are INT (R5 lesson: fp32 LDS atomics = CAS
// loop = 26x slowdown; never fp32 atomics on a hot path).
// ---------------------------------------------------------------------------
#define BIN_CHUNK 4096

__global__ __launch_bounds__(256) void bucket_count(
    const int* __restrict__ ei, int E, int* __restrict__ bcnt) {
  __shared__ int lc[512];
  for (int i = threadIdx.x; i < 512; i += 256) lc[i] = 0;
  __syncthreads();
  const int base = blockIdx.x * BIN_CHUNK;
  for (int k = threadIdx.x; k < BIN_CHUNK; k += 256) {
    int e = base + k;
    if (e < E) atomicAdd(&lc[ei[E + e] >> 7], 1);
  }
  __syncthreads();
  for (int b = threadIdx.x; b < 512; b += 256)
    if (lc[b]) atomicAdd(&bcnt[b], lc[b]);
}

// single block: exclusive scan of nb bucket counts -> boff[0..nb], gcur init
__global__ __launch_bounds__(512) void bucket_scan(
    const int* __restrict__ bcnt, int nb, int* __restrict__ boff,
    int* __restrict__ gcur) {
  __shared__ int sh[512];
  int t = threadIdx.x;
  int v = (t < nb) ? bcnt[t] : 0;
  sh[t] = v;
  __syncthreads();
  int acc = v;
  for (int off = 1; off < 512; off <<= 1) {
    int xx = (t >= off) ? sh[t - off] : 0;
    __syncthreads();
    acc += xx;
    sh[t] = acc;
    __syncthreads();
  }
  if (t < nb) {
    boff[t] = acc - v;
    gcur[t] = acc - v;
  }
  if (t == nb - 1) boff[nb] = acc;
}

// bin-fill: stage chunk in LDS, count per bucket, reserve contiguous runs via
// one global atomic per (wg,bucket), then write records run-contiguously.
// Record: {x = (dst_local<<16) | src  (src < 65536!), y = fp32 weight bits}
__global__ __launch_bounds__(256) void bin_fill(
    const int* __restrict__ ei, const float* __restrict__ ew, int E,
    int* __restrict__ gcur, int2* __restrict__ rec) {
  __shared__ int2 se[BIN_CHUNK];
  __shared__ int scnt[512];
  __shared__ int scur[512];
  for (int i = threadIdx.x; i < 512; i += 256) scnt[i] = 0;
  __syncthreads();
  const int base = blockIdx.x * BIN_CHUNK;
  for (int k = threadIdx.x; k < BIN_CHUNK; k += 256) {
    int e = base + k;
    if (e < E) {
      int src = ei[e];
      int dst = ei[E + e];
      se[k] = make_int2(src, dst);
      atomicAdd(&scnt[dst >> 7], 1);
    }
  }
  __syncthreads();
  for (int b = threadIdx.x; b < 512; b += 256)
    if (scnt[b]) scur[b] = atomicAdd(&gcur[b], scnt[b]);
  __syncthreads();
  for (int k = threadIdx.x; k < BIN_CHUNK; k += 256) {
    int e = base + k;
    if (e < E) {
      int2 sd = se[k];
      int b = sd.y >> 7;
      int pos = atomicAdd(&scur[b], 1);
      rec[pos] = make_int2(((sd.y & 127) << 16) | sd.x, __float_as_int(ew[e]));
    }
  }
}

// ---------------------------------------------------------------------------
// tile_sort: one block per tile. Exact per-dst CSR within the tile's
// contiguous record span. Emits row_ptr. INT LDS atomics only.
// ---------------------------------------------------------------------------
__global__ __launch_bounds__(256) void tile_sort(
    const int2* __restrict__ recRaw, const int* __restrict__ boff,
    int2* __restrict__ recS, int* __restrict__ rp, int N, int nb) {
  __shared__ int cnt[128];
  __shared__ int sc[128];
  __shared__ int cur[128];
  const int tile = blockIdx.x;
  const int lo = boff[tile], hi = boff[tile + 1];
  const int t = threadIdx.x;
  if (t < 128) cnt[t] = 0;
  __syncthreads();
  for (int j = lo + t; j < hi; j += 256)
    atomicAdd(&cnt[recRaw[j].x >> 16], 1);
  __syncthreads();
  if (t < 128) sc[t] = cnt[t];
  __syncthreads();
  for (int off = 1; off < 128; off <<= 1) {
    int v = 0;
    if (t < 128 && t >= off) v = sc[t - off];
    __syncthreads();
    if (t < 128) sc[t] += v;
    __syncthreads();
  }
  if (t < 128) {
    int excl = sc[t] - cnt[t];
    cur[t] = excl;
    int n = tile * 128 + t;
    if (n < N) rp[n] = lo + excl;
  }
  if (tile == nb - 1 && t == 0) rp[N] = hi;
  __syncthreads();
  for (int j = lo + t; j < hi; j += 256) {
    int2 r = recRaw[j];
    int pos = lo + atomicAdd(&cur[r.x >> 16], 1);
    recS[pos] = r;
  }
}

// ---------------------------------------------------------------------------
// Gather-sum (8 independent chains). Records read NONTEMPORALLY (stream-once,
// must not evict the L2-resident feat working set). src = low 16 bits.
// HS = feature-stride of this feat buffer.
// ---------------------------------------------------------------------------
template <int HS>
static __device__ __forceinline__ float gather_sum(
    const int* __restrict__ rp, const int2* __restrict__ rec,
    const unsigned short* __restrict__ feat, int n, int h) {
  int b = rp[n], e = rp[n + 1];
  float a0 = 0.f, a1 = 0.f, a2 = 0.f, a3 = 0.f;
  float a4 = 0.f, a5 = 0.f, a6 = 0.f, a7 = 0.f;
  const long long* recq = (const long long*)rec;
  int j = b;
  for (; j + 8 <= e; j += 8) {
    long long q0 = __builtin_nontemporal_load(recq + j + 0);
    long long q1 = __builtin_nontemporal_load(recq + j + 1);
    long long q2 = __builtin_nontemporal_load(recq + j + 2);
    long long q3 = __builtin_nontemporal_load(recq + j + 3);
    long long q4 = __builtin_nontemporal_load(recq + j + 4);
    long long q5 = __builtin_nontemporal_load(recq + j + 5);
    long long q6 = __builtin_nontemporal_load(recq + j + 6);
    long long q7 = __builtin_nontemporal_load(recq + j + 7);
    a0 += __int_as_float((int)(q0 >> 32)) *
          bf2f(feat[(size_t)(q0 & 0xFFFF) * HS + h]);
    a1 += __int_as_float((int)(q1 >> 32)) *
          bf2f(feat[(size_t)(q1 & 0xFFFF) * HS + h]);
    a2 += __int_as_float((int)(q2 >> 32)) *
          bf2f(feat[(size_t)(q2 & 0xFFFF) * HS + h]);
    a3 += __int_as_float((int)(q3 >> 32)) *
          bf2f(feat[(size_t)(q3 & 0xFFFF) * HS + h]);
    a4 += __int_as_float((int)(q4 >> 32)) *
          bf2f(feat[(size_t)(q4 & 0xFFFF) * HS + h]);
    a5 += __int_as_float((int)(q5 >> 32)) *
          bf2f(feat[(size_t)(q5 & 0xFFFF) * HS + h]);
    a6 += __int_as_float((int)(q6 >> 32)) *
          bf2f(feat[(size_t)(q6 & 0xFFFF) * HS + h]);
    a7 += __int_as_float((int)(q7 >> 32)) *
          bf2f(feat[(size_t)(q7 & 0xFFFF) * HS + h]);
  }
  for (; j < e; ++j) {
    long long q = __builtin_nontemporal_load(recq + j);
    a0 += __int_as_float((int)(q >> 32)) *
          bf2f(feat[(size_t)(q & 0xFFFF) * HS + h]);
  }
  return ((a0 + a1) + (a2 + a3)) + ((a4 + a5) + (a6 + a7));
}

// ---------------------------------------------------------------------------
// Layer-0 fused aggregate+combine over ONE 32-column feat half.
// Wave covers 2 nodes x 32 feature lanes. Working set 3.2 MB -> L2-resident.
// ---------------------------------------------------------------------------
__global__ __launch_bounds__(256) void agg_combine32(
    const int* __restrict__ rpA, const int2* __restrict__ recA,
    const int* __restrict__ rpK, const int2* __restrict__ recK,
    const unsigned short* __restrict__ feat32, const float* __restrict__ s,
    const float* __restrict__ Dk, unsigned short* __restrict__ out32, int N) {
  int tid = blockIdx.x * 256 + threadIdx.x;
  int n = tid >> 5;
  int h = tid & 31;
  if (n >= N) return;
  float aA = gather_sum<32>(rpA, recA, feat32, n, h);
  float aK = gather_sum<32>(rpK, recK, feat32, n, h);
  float sv = s[n];
  float res = sv * aA + (1.f - sv) * aK +
              GAMMA * Dk[n] * bf2f(feat32[(size_t)n * 32 + h]);
  out32[(size_t)n * 32 + h] = f2bf(res);
}

// ---------------------------------------------------------------------------
// Layer-1 fused aggregate+combine (packed N x 16 feat, fp32 out).
// ---------------------------------------------------------------------------
__global__ __launch_bounds__(256) void agg_combine16(
    const int* __restrict__ rpA, const int2* __restrict__ recA,
    const int* __restrict__ rpK, const int2* __restrict__ recK,
    const unsigned short* __restrict__ feat, const float* __restrict__ s,
    const float* __restrict__ Dk, float* __restrict__ outp, int N) {
  int tid = blockIdx.x * 256 + threadIdx.x;
  int n = tid >> 4;
  int h = tid & 15;
  if (n >= N) return;
  float aA = gather_sum<16>(rpA, recA, feat, n, h);
  float aK = gather_sum<16>(rpK, recK, feat, n, h);
  float sv = s[n];
  float res = sv * aA + (1.f - sv) * aK +
              GAMMA * Dk[n] * bf2f(feat[(size_t)n * 16 + h]);
  outp[(size_t)n * 16 + h] = res;
}

// ---------------------------------------------------------------------------
extern "C" void kernel_launch(void* const* d_in, const int* in_sizes, int n_in,
                              void* d_out, int out_size, void* d_ws, size_t ws_size,
                              hipStream_t stream) {
  const float* x = (const float*)d_in[0];
  const int* edge_index = (const int*)d_in[1];
  const float* edge_weight = (const float*)d_in[2];
  const int* knn_edge_index = (const int*)d_in[3];
  const float* knn_edge_weight = (const float*)d_in[4];
  const float* W0 = (const float*)d_in[5];
  const float* W1 = (const float*)d_in[6];
  const float* score0 = (const float*)d_in[7];
  const float* sbias0 = (const float*)d_in[8];
  const float* score1 = (const float*)d_in[9];
  const float* sbias1 = (const float*)d_in[10];
  const float* Dk0 = (const float*)d_in[11];
  const float* Dbias0 = (const float*)d_in[12];
  const float* Dk1 = (const float*)d_in[13];
  const float* Dbias1 = (const float*)d_in[14];

  const int F = in_sizes[7];          // 500
  const int N = in_sizes[0] / F;      // 50000 (< 65536: src packed in 16 bits)
  const int E = in_sizes[2];          // 1.6M
  const int Ek = in_sizes[4];         // 1.0M
  (void)n_in; (void)ws_size; (void)out_size;

  const int nb = (N + 127) / 128;     // 391 dst tiles (<= 512)

  // ---- workspace bump allocator (256B-aligned slices) ----
  char* cur = (char*)d_ws;
  auto alloc = [&](size_t bytes) {
    char* p = cur;
    cur += (bytes + 255) & ~(size_t)255;
    return (void*)p;
  };
  float* sbuf = (float*)alloc((size_t)N * 4);
  float* dkbuf = (float*)alloc((size_t)N * 4);
  int* bcnt2 = (int*)alloc((size_t)2 * nb * 4);   // ONE slice: memset covers both
  int* bcntA = bcnt2;
  int* bcntK = bcnt2 + nb;
  int* boffA = (int*)alloc((size_t)(nb + 1) * 4);
  int* boffK = (int*)alloc((size_t)(nb + 1) * 4);
  int* gcurA = (int*)alloc((size_t)nb * 4);
  int* gcurK = (int*)alloc((size_t)nb * 4);
  int* rpA = (int*)alloc((size_t)(N + 1) * 4);
  int* rpK = (int*)alloc((size_t)(N + 1) * 4);
  int2* recA = (int2*)alloc((size_t)E * 8);       // sorted (exact CSR)
  int2* recK = (int2*)alloc((size_t)Ek * 8);
  unsigned short* Bt0 = (unsigned short*)alloc((size_t)80 * 512 * 2);
  unsigned short* Bt1 = (unsigned short*)alloc((size_t)32 * 64 * 2);
  // UNION region: recRaw (dead after tile_sort) overlaps the feature buffers
  // (written only after tile_sort completes; same stream => safe).
  char* uni = (char*)alloc((size_t)(E + Ek) * 8);
  int2* recRawA = (int2*)uni;
  int2* recRawK = recRawA + E;
  unsigned short* xW_lo = (unsigned short*)uni;            // N*32
  unsigned short* xW_hi = xW_lo + (size_t)N * 32;          // N*32
  unsigned short* x1_lo = xW_hi + (size_t)N * 32;          // N*32
  unsigned short* x1_hi = x1_lo + (size_t)N * 32;          // N*32
  unsigned short* xW1b = x1_hi + (size_t)N * 32;           // N*16

  // ---- B transposes (tiny) ----
  build_bt<<<(80 * 512 + 255) / 256, 256, 0, stream>>>(W0, score0, Dk0, Bt0,
                                                       64, F, 512, 80);
  build_bt<<<(32 * 64 + 255) / 256, 256, 0, stream>>>(W1, score1, Dk1, Bt1,
                                                      16, 64, 64, 32);

  // ---- tile binning + exact CSR (reused by both layers) ----
  hipMemsetAsync(bcnt2, 0, (size_t)2 * nb * sizeof(int), stream);
  const int nchA = (E + BIN_CHUNK - 1) / BIN_CHUNK;
  const int nchK = (Ek + BIN_CHUNK - 1) / BIN_CHUNK;
  bucket_count<<<nchA, 256, 0, stream>>>(edge_index, E, bcntA);
  bucket_count<<<nchK, 256, 0, stream>>>(knn_edge_index, Ek, bcntK);
  bucket_scan<<<1, 512, 0, stream>>>(bcntA, nb, boffA, gcurA);
  bucket_scan<<<1, 512, 0, stream>>>(bcntK, nb, boffK, gcurK);
  bin_fill<<<nchA, 256, 0, stream>>>(edge_index, edge_weight, E, gcurA,
                                     recRawA);
  bin_fill<<<nchK, 256, 0, stream>>>(knn_edge_index, knn_edge_weight, Ek,
                                     gcurK, recRawK);
  tile_sort<<<nb, 256, 0, stream>>>(recRawA, boffA, recA, rpA, N, nb);
  tile_sort<<<nb, 256, 0, stream>>>(recRawK, boffK, recK, rpK, N, nb);

  const int gemmBlocks = (N + 63) / 64;
  const int aggBlocks32 = (int)(((size_t)N * 32 + 255) / 256);
  const int aggBlocks16 = (int)(((size_t)N * 16 + 255) / 256);

  // ---- Layer 0: F=500 -> H=64 (+gate+Dk), split output ----
  mfma_linear<512, 5, 4, false, true><<<gemmBlocks, 256, 0, stream>>>(
      x, nullptr, Bt0, sbias0, Dbias0, xW_lo, xW_hi, sbuf, dkbuf, N, F);
  agg_combine32<<<aggBlocks32, 256, 0, stream>>>(rpA, recA, rpK, recK, xW_lo,
                                                 sbuf, dkbuf, x1_lo, N);
  agg_combine32<<<aggBlocks32, 256, 0, stream>>>(rpA, recA, rpK, recK, xW_hi,
                                                 sbuf, dkbuf, x1_hi, N);

  // ---- Layer 1: H=64 (split A) -> O=16 (+gate+Dk), packed output ----
  mfma_linear<64, 2, 1, true, false><<<gemmBlocks, 256, 0, stream>>>(
      x1_lo, x1_hi, Bt1, sbias1, Dbias1, xW1b, nullptr, sbuf, dkbuf, N, 64);
  agg_combine16<<<aggBlocks16, 256, 0, stream>>>(rpA, recA, rpK, recK, xW1b,
                                                 sbuf, dkbuf, (float*)d_out, N);
}

// Round 10
// 256.113 us; speedup vs baseline: 1.3332x; 1.3332x over previous
//
#include <hip/hip_runtime.h>
#include <math.h>

#define GAMMA 0.1f

typedef float f32x4 __attribute__((ext_vector_type(4)));
typedef short short8 __attribute__((ext_vector_type(8)));

static __device__ __forceinline__ unsigned short f2bf(float f) {
  union { float f; unsigned u; } v; v.f = f;
  unsigned r = v.u + 0x7FFF + ((v.u >> 16) & 1);   // RNE
  return (unsigned short)(r >> 16);
}
static __device__ __forceinline__ float bf2f(unsigned short b) {
  union { unsigned u; float f; } v; v.u = ((unsigned)b) << 16;
  return v.f;
}

// ---------------------------------------------------------------------------
// Build transposed bf16 B matrix: Bt[c][k], c in [0,COLS), k in [0,KPAD)
//   c < H : W[k][c];  c == H : sc[k];  c == H+1 : dk[k];  else/k>=Kact : 0
// ---------------------------------------------------------------------------
__global__ __launch_bounds__(256) void build_bt(
    const float* __restrict__ W, const float* __restrict__ sc,
    const float* __restrict__ dk, unsigned short* __restrict__ Bt,
    int H, int Kact, int KPAD, int COLS) {
  int i = blockIdx.x * 256 + threadIdx.x;
  if (i >= COLS * KPAD) return;
  int c = i / KPAD;
  int k = i - c * KPAD;
  float v = 0.f;
  if (k < Kact) {
    if (c < H) v = W[(size_t)k * H + c];
    else if (c == H) v = sc[k];
    else if (c == H + 1) v = dk[k];
  }
  Bt[i] = f2bf(v);
}

// ---------------------------------------------------------------------------
// Fused MFMA linear with K-split: 4 waves = RG row-groups x KSPLIT K-slices.
// KSPLIT=2 doubles wave-parallelism (R7: occupancy 26% = latency-bound).
// Partial accumulators reduced through LDS; kslice-0 waves do the epilogue.
// ---------------------------------------------------------------------------
template <int KPAD, int CFRAGS, int OUTFRAGS, bool ABF, int KSPLIT>
__global__ __launch_bounds__(256) void mfma_linear(
    const void* __restrict__ Aptr, const unsigned short* __restrict__ Bt,
    const float* __restrict__ sb, const float* __restrict__ db,
    unsigned short* __restrict__ outW, float* __restrict__ s,
    float* __restrict__ Dk, int N, int Kact) {
  constexpr int H = OUTFRAGS * 16;
  constexpr int NKS = KPAD / 32;
  constexpr int RG = 4 / KSPLIT;        // row-groups per block
  constexpr int RPB = RG * 16;          // rows per block
  constexpr int KS_PER = NKS / KSPLIT;  // ks steps per K-slice
  constexpr int REDSZ = (KSPLIT > 1) ? (KSPLIT - 1) * RG * 64 * CFRAGS * 4 : 1;
  __shared__ float red[REDSZ];

  const int w = threadIdx.x >> 6;
  const int rowgrp = w % RG;
  const int kslice = w / RG;
  const int l = threadIdx.x & 63;
  const int kgrp = l >> 4;          // 0..3
  const int lc = l & 15;
  const int rowA = blockIdx.x * RPB + rowgrp * 16 + lc;
  const int rowD = blockIdx.x * RPB + rowgrp * 16 + kgrp * 4;

  f32x4 acc[CFRAGS];
#pragma unroll
  for (int i = 0; i < CFRAGS; ++i) acc[i] = (f32x4)0.f;

  for (int ks = kslice * KS_PER; ks < kslice * KS_PER + KS_PER; ++ks) {
    const int kb = ks * 32 + kgrp * 8;
    short8 av;
    if (rowA < N) {
      if (ABF) {
        av = *(const short8*)((const unsigned short*)Aptr +
                              (size_t)rowA * Kact + kb);
      } else {
        const float* A = (const float*)Aptr + (size_t)rowA * Kact;
        if (kb + 8 <= Kact) {
          f32x4 f0 = *(const f32x4*)(A + kb);
          f32x4 f1 = *(const f32x4*)(A + kb + 4);
#pragma unroll
          for (int j = 0; j < 4; ++j) {
            av[j] = (short)f2bf(f0[j]);
            av[j + 4] = (short)f2bf(f1[j]);
          }
        } else {
#pragma unroll
          for (int j = 0; j < 8; ++j) {
            int f = kb + j;
            av[j] = (short)f2bf(f < Kact ? A[f] : 0.f);
          }
        }
      }
    } else {
#pragma unroll
      for (int j = 0; j < 8; ++j) av[j] = 0;
    }

#pragma unroll
    for (int fc = 0; fc < CFRAGS; ++fc) {
      short8 bv = *(const short8*)(Bt + (size_t)(fc * 16 + lc) * KPAD + kb);
      acc[fc] = __builtin_amdgcn_mfma_f32_16x16x32_bf16(av, bv, acc[fc], 0, 0, 0);
    }
  }

  if constexpr (KSPLIT > 1) {
    if (kslice > 0) {
      float* dst =
          red + (((kslice - 1) * RG + rowgrp) * 64 + l) * (CFRAGS * 4);
#pragma unroll
      for (int fc = 0; fc < CFRAGS; ++fc)
#pragma unroll
        for (int r = 0; r < 4; ++r) dst[fc * 4 + r] = acc[fc][r];
    }
    __syncthreads();
    if (kslice == 0) {
#pragma unroll
      for (int s2 = 1; s2 < KSPLIT; ++s2) {
        const float* src2 =
            red + (((s2 - 1) * RG + rowgrp) * 64 + l) * (CFRAGS * 4);
#pragma unroll
        for (int fc = 0; fc < CFRAGS; ++fc)
#pragma unroll
          for (int r = 0; r < 4; ++r) acc[fc][r] += src2[fc * 4 + r];
      }
    }
  }

  if (kslice == 0) {
    // epilogue: xW (bf16, packed)
#pragma unroll
    for (int fc = 0; fc < OUTFRAGS; ++fc) {
#pragma unroll
      for (int r = 0; r < 4; ++r) {
        int gr = rowD + r;
        if (gr < N) outW[(size_t)gr * H + fc * 16 + lc] = f2bf(acc[fc][r]);
      }
    }
    // gate + degree columns live in the last fragment (local cols 0 and 1)
    if (lc < 2) {
      f32x4 g = acc[CFRAGS - 1];
#pragma unroll
      for (int r = 0; r < 4; ++r) {
        int gr = rowD + r;
        if (gr < N) {
          if (lc == 0) s[gr] = 1.f / (1.f + expf(-(g[r] + sb[0])));
          else Dk[gr] = g[r] + db[0];
        }
      }
    }
  }
}

// ---------------------------------------------------------------------------
// Tile binning: bucket = dst >> 7 (128-node tiles). nb <= 512 assumed.
// All histogram/cursor atomics are INT (R5 lesson: fp32 LDS atomics = CAS
// loop = 26x slowdown; never fp32 atomics on a hot path).
// ---------------------------------------------------------------------------
#define BIN_CHUNK 4096

__global__ __launch_bounds__(256) void bucket_count(
    const int* __restrict__ ei, int E, int* __restrict__ bcnt) {
  __shared__ int lc[512];
  for (int i = threadIdx.x; i < 512; i += 256) lc[i] = 0;
  __syncthreads();
  const int base = blockIdx.x * BIN_CHUNK;
  for (int k = threadIdx.x; k < BIN_CHUNK; k += 256) {
    int e = base + k;
    if (e < E) atomicAdd(&lc[ei[E + e] >> 7], 1);
  }
  __syncthreads();
  for (int b = threadIdx.x; b < 512; b += 256)
    if (lc[b]) atomicAdd(&bcnt[b], lc[b]);
}

// single block: exclusive scan of nb bucket counts -> boff[0..nb], gcur init
__global__ __launch_bounds__(512) void bucket_scan(
    const int* __restrict__ bcnt, int nb, int* __restrict__ boff,
    int* __restrict__ gcur) {
  __shared__ int sh[512];
  int t = threadIdx.x;
  int v = (t < nb) ? bcnt[t] : 0;
  sh[t] = v;
  __syncthreads();
  int acc = v;
  for (int off = 1; off < 512; off <<= 1) {
    int xx = (t >= off) ? sh[t - off] : 0;
    __syncthreads();
    acc += xx;
    sh[t] = acc;
    __syncthreads();
  }
  if (t < nb) {
    boff[t] = acc - v;
    gcur[t] = acc - v;
  }
  if (t == nb - 1) boff[nb] = acc;
}

// bin-fill: stage chunk in LDS, count per bucket, reserve contiguous runs via
// one global atomic per (wg,bucket), then write records run-contiguously.
// Record: {x = (dst_local<<16) | src  (src < 65536!), y = fp32 weight bits}
__global__ __launch_bounds__(256) void bin_fill(
    const int* __restrict__ ei, const float* __restrict__ ew, int E,
    int* __restrict__ gcur, int2* __restrict__ rec) {
  __shared__ int2 se[BIN_CHUNK];
  __shared__ int scnt[512];
  __shared__ int scur[512];
  for (int i = threadIdx.x; i < 512; i += 256) scnt[i] = 0;
  __syncthreads();
  const int base = blockIdx.x * BIN_CHUNK;
  for (int k = threadIdx.x; k < BIN_CHUNK; k += 256) {
    int e = base + k;
    if (e < E) {
      int src = ei[e];
      int dst = ei[E + e];
      se[k] = make_int2(src, dst);
      atomicAdd(&scnt[dst >> 7], 1);
    }
  }
  __syncthreads();
  for (int b = threadIdx.x; b < 512; b += 256)
    if (scnt[b]) scur[b] = atomicAdd(&gcur[b], scnt[b]);
  __syncthreads();
  for (int k = threadIdx.x; k < BIN_CHUNK; k += 256) {
    int e = base + k;
    if (e < E) {
      int2 sd = se[k];
      int b = sd.y >> 7;
      int pos = atomicAdd(&scur[b], 1);
      rec[pos] = make_int2(((sd.y & 127) << 16) | sd.x, __float_as_int(ew[e]));
    }
  }
}

// ---------------------------------------------------------------------------
// tile_sort: one block per tile. Exact per-dst CSR within the tile's
// contiguous record span. Emits row_ptr. INT LDS atomics only.
// ---------------------------------------------------------------------------
__global__ __launch_bounds__(256) void tile_sort(
    const int2* __restrict__ recRaw, const int* __restrict__ boff,
    int2* __restrict__ recS, int* __restrict__ rp, int N, int nb) {
  __shared__ int cnt[128];
  __shared__ int sc[128];
  __shared__ int cur[128];
  const int tile = blockIdx.x;
  const int lo = boff[tile], hi = boff[tile + 1];
  const int t = threadIdx.x;
  if (t < 128) cnt[t] = 0;
  __syncthreads();
  for (int j = lo + t; j < hi; j += 256)
    atomicAdd(&cnt[recRaw[j].x >> 16], 1);
  __syncthreads();
  if (t < 128) sc[t] = cnt[t];
  __syncthreads();
  for (int off = 1; off < 128; off <<= 1) {
    int v = 0;
    if (t < 128 && t >= off) v = sc[t - off];
    __syncthreads();
    if (t < 128) sc[t] += v;
    __syncthreads();
  }
  if (t < 128) {
    int excl = sc[t] - cnt[t];
    cur[t] = excl;
    int n = tile * 128 + t;
    if (n < N) rp[n] = lo + excl;
  }
  if (tile == nb - 1 && t == 0) rp[N] = hi;
  __syncthreads();
  for (int j = lo + t; j < hi; j += 256) {
    int2 r = recRaw[j];
    int pos = lo + atomicAdd(&cur[r.x >> 16], 1);
    recS[pos] = r;
  }
}

// ---------------------------------------------------------------------------
// Layer-0 gather: one wave per node (64 feature lanes). Node index is
// wave-uniform (readfirstlane) so rp/rec loads can select to the scalar
// (SMEM) path; 16 independent chains for memory-level parallelism.
// ---------------------------------------------------------------------------
static __device__ __forceinline__ float gather64(
    const int* __restrict__ rp, const int2* __restrict__ rec,
    const unsigned short* __restrict__ feat, int n, int h) {
  int b = rp[n], e = rp[n + 1];
  float a[16];
#pragma unroll
  for (int u = 0; u < 16; ++u) a[u] = 0.f;
  int j = b;
  for (; j + 16 <= e; j += 16) {
#pragma unroll
    for (int u = 0; u < 16; ++u) {
      int2 r = rec[j + u];
      a[u] += __int_as_float(r.y) *
              bf2f(feat[(size_t)(r.x & 0xFFFF) * 64 + h]);
    }
  }
  for (; j + 4 <= e; j += 4) {
#pragma unroll
    for (int u = 0; u < 4; ++u) {
      int2 r = rec[j + u];
      a[u] += __int_as_float(r.y) *
              bf2f(feat[(size_t)(r.x & 0xFFFF) * 64 + h]);
    }
  }
  for (; j < e; ++j) {
    int2 r = rec[j];
    a[0] += __int_as_float(r.y) * bf2f(feat[(size_t)(r.x & 0xFFFF) * 64 + h]);
  }
  float t0 = ((a[0] + a[1]) + (a[2] + a[3])) + ((a[4] + a[5]) + (a[6] + a[7]));
  float t1 = ((a[8] + a[9]) + (a[10] + a[11])) +
             ((a[12] + a[13]) + (a[14] + a[15]));
  return t0 + t1;
}

__global__ __launch_bounds__(256) void agg_combine64(
    const int* __restrict__ rpA, const int2* __restrict__ recA,
    const int* __restrict__ rpK, const int2* __restrict__ recK,
    const unsigned short* __restrict__ feat, const float* __restrict__ s,
    const float* __restrict__ Dk, unsigned short* __restrict__ outp, int N) {
  int n = __builtin_amdgcn_readfirstlane((blockIdx.x * 256 + threadIdx.x) >> 6);
  if (n >= N) return;
  int h = threadIdx.x & 63;
  float aA = gather64(rpA, recA, feat, n, h);
  float aK = gather64(rpK, recK, feat, n, h);
  float sv = s[n];
  float res = sv * aA + (1.f - sv) * aK +
              GAMMA * Dk[n] * bf2f(feat[(size_t)n * 64 + h]);
  outp[(size_t)n * 64 + h] = f2bf(res);
}

// ---------------------------------------------------------------------------
// Layer-1 gather (H=16, 4 nodes per wave): vector loads, 8 chains.
// ---------------------------------------------------------------------------
static __device__ __forceinline__ float gather16(
    const int* __restrict__ rp, const int2* __restrict__ rec,
    const unsigned short* __restrict__ feat, int n, int h) {
  int b = rp[n], e = rp[n + 1];
  float a0 = 0.f, a1 = 0.f, a2 = 0.f, a3 = 0.f;
  float a4 = 0.f, a5 = 0.f, a6 = 0.f, a7 = 0.f;
  const long long* recq = (const long long*)rec;
  int j = b;
  for (; j + 8 <= e; j += 8) {
    long long q0 = __builtin_nontemporal_load(recq + j + 0);
    long long q1 = __builtin_nontemporal_load(recq + j + 1);
    long long q2 = __builtin_nontemporal_load(recq + j + 2);
    long long q3 = __builtin_nontemporal_load(recq + j + 3);
    long long q4 = __builtin_nontemporal_load(recq + j + 4);
    long long q5 = __builtin_nontemporal_load(recq + j + 5);
    long long q6 = __builtin_nontemporal_load(recq + j + 6);
    long long q7 = __builtin_nontemporal_load(recq + j + 7);
    a0 += __int_as_float((int)(q0 >> 32)) *
          bf2f(feat[(size_t)(q0 & 0xFFFF) * 16 + h]);
    a1 += __int_as_float((int)(q1 >> 32)) *
          bf2f(feat[(size_t)(q1 & 0xFFFF) * 16 + h]);
    a2 += __int_as_float((int)(q2 >> 32)) *
          bf2f(feat[(size_t)(q2 & 0xFFFF) * 16 + h]);
    a3 += __int_as_float((int)(q3 >> 32)) *
          bf2f(feat[(size_t)(q3 & 0xFFFF) * 16 + h]);
    a4 += __int_as_float((int)(q4 >> 32)) *
          bf2f(feat[(size_t)(q4 & 0xFFFF) * 16 + h]);
    a5 += __int_as_float((int)(q5 >> 32)) *
          bf2f(feat[(size_t)(q5 & 0xFFFF) * 16 + h]);
    a6 += __int_as_float((int)(q6 >> 32)) *
          bf2f(feat[(size_t)(q6 & 0xFFFF) * 16 + h]);
    a7 += __int_as_float((int)(q7 >> 32)) *
          bf2f(feat[(size_t)(q7 & 0xFFFF) * 16 + h]);
  }
  for (; j < e; ++j) {
    long long q = __builtin_nontemporal_load(recq + j);
    a0 += __int_as_float((int)(q >> 32)) *
          bf2f(feat[(size_t)(q & 0xFFFF) * 16 + h]);
  }
  return ((a0 + a1) + (a2 + a3)) + ((a4 + a5) + (a6 + a7));
}

__global__ __launch_bounds__(256) void agg_combine16(
    const int* __restrict__ rpA, const int2* __restrict__ recA,
    const int* __restrict__ rpK, const int2* __restrict__ recK,
    const unsigned short* __restrict__ feat, const float* __restrict__ s,
    const float* __restrict__ Dk, float* __restrict__ outp, int N) {
  int tid = blockIdx.x * 256 + threadIdx.x;
  int n = tid >> 4;
  int h = tid & 15;
  if (n >= N) return;
  float aA = gather16(rpA, recA, feat, n, h);
  float aK = gather16(rpK, recK, feat, n, h);
  float sv = s[n];
  float res = sv * aA + (1.f - sv) * aK +
              GAMMA * Dk[n] * bf2f(feat[(size_t)n * 16 + h]);
  outp[(size_t)n * 16 + h] = res;
}

// ---------------------------------------------------------------------------
extern "C" void kernel_launch(void* const* d_in, const int* in_sizes, int n_in,
                              void* d_out, int out_size, void* d_ws, size_t ws_size,
                              hipStream_t stream) {
  const float* x = (const float*)d_in[0];
  const int* edge_index = (const int*)d_in[1];
  const float* edge_weight = (const float*)d_in[2];
  const int* knn_edge_index = (const int*)d_in[3];
  const float* knn_edge_weight = (const float*)d_in[4];
  const float* W0 = (const float*)d_in[5];
  const float* W1 = (const float*)d_in[6];
  const float* score0 = (const float*)d_in[7];
  const float* sbias0 = (const float*)d_in[8];
  const float* score1 = (const float*)d_in[9];
  const float* sbias1 = (const float*)d_in[10];
  const float* Dk0 = (const float*)d_in[11];
  const float* Dbias0 = (const float*)d_in[12];
  const float* Dk1 = (const float*)d_in[13];
  const float* Dbias1 = (const float*)d_in[14];

  const int F = in_sizes[7];          // 500
  const int N = in_sizes[0] / F;      // 50000 (< 65536: src packed in 16 bits)
  const int E = in_sizes[2];          // 1.6M
  const int Ek = in_sizes[4];         // 1.0M
  (void)n_in; (void)ws_size; (void)out_size;

  const int nb = (N + 127) / 128;     // 391 dst tiles (<= 512)

  // ---- workspace bump allocator (256B-aligned slices) ----
  char* cur = (char*)d_ws;
  auto alloc = [&](size_t bytes) {
    char* p = cur;
    cur += (bytes + 255) & ~(size_t)255;
    return (void*)p;
  };
  float* sbuf = (float*)alloc((size_t)N * 4);
  float* dkbuf = (float*)alloc((size_t)N * 4);
  int* bcnt2 = (int*)alloc((size_t)2 * nb * 4);   // ONE slice: memset covers both
  int* bcntA = bcnt2;
  int* bcntK = bcnt2 + nb;
  int* boffA = (int*)alloc((size_t)(nb + 1) * 4);
  int* boffK = (int*)alloc((size_t)(nb + 1) * 4);
  int* gcurA = (int*)alloc((size_t)nb * 4);
  int* gcurK = (int*)alloc((size_t)nb * 4);
  int* rpA = (int*)alloc((size_t)(N + 1) * 4);
  int* rpK = (int*)alloc((size_t)(N + 1) * 4);
  int2* recA = (int2*)alloc((size_t)E * 8);       // sorted (exact CSR)
  int2* recK = (int2*)alloc((size_t)Ek * 8);
  unsigned short* Bt0 = (unsigned short*)alloc((size_t)80 * 512 * 2);
  unsigned short* Bt1 = (unsigned short*)alloc((size_t)32 * 64 * 2);
  // UNION region: recRaw (dead after tile_sort) overlaps the feature buffers
  // (written only after tile_sort completes; same stream => safe).
  char* uni = (char*)alloc((size_t)(E + Ek) * 8);
  int2* recRawA = (int2*)uni;
  int2* recRawK = recRawA + E;
  unsigned short* xWb = (unsigned short*)uni;              // N*64
  unsigned short* x1b = xWb + (size_t)N * 64;              // N*64
  unsigned short* xW1b = x1b + (size_t)N * 64;             // N*16

  // ---- B transposes (tiny) ----
  build_bt<<<(80 * 512 + 255) / 256, 256, 0, stream>>>(W0, score0, Dk0, Bt0,
                                                       64, F, 512, 80);
  build_bt<<<(32 * 64 + 255) / 256, 256, 0, stream>>>(W1, score1, Dk1, Bt1,
                                                      16, 64, 64, 32);

  // ---- tile binning + exact CSR (reused by both layers) ----
  hipMemsetAsync(bcnt2, 0, (size_t)2 * nb * sizeof(int), stream);
  const int nchA = (E + BIN_CHUNK - 1) / BIN_CHUNK;
  const int nchK = (Ek + BIN_CHUNK - 1) / BIN_CHUNK;
  bucket_count<<<nchA, 256, 0, stream>>>(edge_index, E, bcntA);
  bucket_count<<<nchK, 256, 0, stream>>>(knn_edge_index, Ek, bcntK);
  bucket_scan<<<1, 512, 0, stream>>>(bcntA, nb, boffA, gcurA);
  bucket_scan<<<1, 512, 0, stream>>>(bcntK, nb, boffK, gcurK);
  bin_fill<<<nchA, 256, 0, stream>>>(edge_index, edge_weight, E, gcurA,
                                     recRawA);
  bin_fill<<<nchK, 256, 0, stream>>>(knn_edge_index, knn_edge_weight, Ek,
                                     gcurK, recRawK);
  tile_sort<<<nb, 256, 0, stream>>>(recRawA, boffA, recA, rpA, N, nb);
  tile_sort<<<nb, 256, 0, stream>>>(recRawK, boffK, recK, rpK, N, nb);

  const int gemmBlocks = (N + 31) / 32;           // 32 rows/block (K-split 2)
  const int agg64Blocks = (int)(((size_t)N * 64 + 255) / 256);
  const int agg16Blocks = (int)(((size_t)N * 16 + 255) / 256);

  // ---- Layer 0: F=500 -> H=64 (+gate+Dk) ----
  mfma_linear<512, 5, 4, false, 2><<<gemmBlocks, 256, 0, stream>>>(
      x, Bt0, sbias0, Dbias0, xWb, sbuf, dkbuf, N, F);
  agg_combine64<<<agg64Blocks, 256, 0, stream>>>(rpA, recA, rpK, recK, xWb,
                                                 sbuf, dkbuf, x1b, N);

  // ---- Layer 1: H=64 -> O=16 (+gate+Dk) ----
  mfma_linear<64, 2, 1, true, 2><<<gemmBlocks, 256, 0, stream>>>(
      x1b, Bt1, sbias1, Dbias1, xW1b, sbuf, dkbuf, N, 64);
  agg_combine16<<<agg16Blocks, 256, 0, stream>>>(rpA, recA, rpK, recK, xW1b,
                                                 sbuf, dkbuf, (float*)d_out, N);
}

// Round 11
// 238.489 us; speedup vs baseline: 1.4317x; 1.0739x over previous
//
#include <hip/hip_runtime.h>
#include <math.h>

#define GAMMA 0.1f

typedef float f32x4 __attribute__((ext_vector_type(4)));
typedef short short8 __attribute__((ext_vector_type(8)));

static __device__ __forceinline__ unsigned short f2bf(float f) {
  union { float f; unsigned u; } v; v.f = f;
  unsigned r = v.u + 0x7FFF + ((v.u >> 16) & 1);   // RNE
  return (unsigned short)(r >> 16);
}
static __device__ __forceinline__ float bf2f(unsigned short b) {
  union { unsigned u; float f; } v; v.u = ((unsigned)b) << 16;
  return v.f;
}

// ---------------------------------------------------------------------------
// Build K-chunk-major bf16 B: entry e = (k/8)*COLS + c holds Bt[c][k8..k8+8).
// Lane-consecutive cols -> coalesced, fully-utilized lines in the GEMM
// (R10 lesson: col-major Bt rows at 1KB stride = ~32 split lines/instr,
// TA-throughput-bound; occupancy-invariant 69us).
//   c < H : W[k][c];  c == H : sc[k];  c == H+1 : dk[k];  else/k>=Kact : 0
// ---------------------------------------------------------------------------
__global__ __launch_bounds__(256) void build_bt3(
    const float* __restrict__ W, const float* __restrict__ sc,
    const float* __restrict__ dk, unsigned short* __restrict__ Bt3,
    int H, int Kact, int KPAD, int COLS) {
  int i = blockIdx.x * 256 + threadIdx.x;
  if (i >= COLS * KPAD) return;
  int c = i / KPAD;
  int k = i - c * KPAD;
  float v = 0.f;
  if (k < Kact) {
    if (c < H) v = W[(size_t)k * H + c];
    else if (c == H) v = sc[k];
    else if (c == H + 1) v = dk[k];
  }
  Bt3[(size_t)((k >> 3) * COLS + c) * 8 + (k & 7)] = f2bf(v);
}

// ---------------------------------------------------------------------------
// Fused MFMA linear, K-split (4 waves = RG row-groups x KSPLIT K-slices).
// A row clamped (no in-loop branch); K-tail split out of the fast loop so the
// compiler can software-pipeline the unrolled A/B loads.
// ---------------------------------------------------------------------------
template <int KPAD, int CFRAGS, int OUTFRAGS, bool ABF, int KSPLIT, int COLS>
__global__ __launch_bounds__(256) void mfma_linear(
    const void* __restrict__ Aptr, const unsigned short* __restrict__ Bt3,
    const float* __restrict__ sb, const float* __restrict__ db,
    unsigned short* __restrict__ outW, float* __restrict__ s,
    float* __restrict__ Dk, int N, int Kact) {
  constexpr int H = OUTFRAGS * 16;
  constexpr int NKS = KPAD / 32;
  constexpr int RG = 4 / KSPLIT;        // row-groups per block
  constexpr int RPB = RG * 16;          // rows per block
  constexpr int KS_PER = NKS / KSPLIT;  // ks steps per K-slice
  constexpr int REDSZ = (KSPLIT > 1) ? (KSPLIT - 1) * RG * 64 * CFRAGS * 4 : 1;
  __shared__ float red[REDSZ];

  const int w = threadIdx.x >> 6;
  const int rowgrp = w % RG;
  const int kslice = w / RG;
  const int l = threadIdx.x & 63;
  const int kgrp = l >> 4;          // 0..3
  const int lc = l & 15;
  const int rowA = blockIdx.x * RPB + rowgrp * 16 + lc;
  const int rowD = blockIdx.x * RPB + rowgrp * 16 + kgrp * 4;
  const bool rowOK = rowA < N;
  const int rowSafe = rowOK ? rowA : 0;   // clamped: loop is branch-free

  f32x4 acc[CFRAGS];
#pragma unroll
  for (int i = 0; i < CFRAGS; ++i) acc[i] = (f32x4)0.f;

  const int ksBeg = kslice * KS_PER;
  const int ksEnd = ksBeg + KS_PER;
  const int ktail = Kact / 32;          // first ks needing masking (15 for 500)
  const int ksFast = (ksEnd < ktail) ? ksEnd : ktail;

#pragma unroll 4
  for (int ks = ksBeg; ks < ksFast; ++ks) {
    const int kb = ks * 32 + kgrp * 8;
    short8 av;
    if (ABF) {
      av = *(const short8*)((const unsigned short*)Aptr +
                            (size_t)rowSafe * Kact + kb);
    } else {
      const float* A = (const float*)Aptr + (size_t)rowSafe * Kact;
      f32x4 f0 = *(const f32x4*)(A + kb);
      f32x4 f1 = *(const f32x4*)(A + kb + 4);
#pragma unroll
      for (int j = 0; j < 4; ++j) {
        av[j] = (short)f2bf(f0[j]);
        av[j + 4] = (short)f2bf(f1[j]);
      }
    }
    const unsigned short* bbase =
        Bt3 + (size_t)((ks * 4 + kgrp) * COLS + lc) * 8;
#pragma unroll
    for (int fc = 0; fc < CFRAGS; ++fc) {
      short8 bv = *(const short8*)(bbase + fc * 128);
      acc[fc] = __builtin_amdgcn_mfma_f32_16x16x32_bf16(av, bv, acc[fc], 0, 0, 0);
    }
  }

  // K tail (ks in [max(ksBeg,ktail), ksEnd)): per-element masked A loads.
  for (int ks = (ksBeg > ktail ? ksBeg : ktail); ks < ksEnd; ++ks) {
    const int kb = ks * 32 + kgrp * 8;
    short8 av;
    if (ABF) {
      av = *(const short8*)((const unsigned short*)Aptr +
                            (size_t)rowSafe * Kact + kb);
    } else {
      const float* A = (const float*)Aptr + (size_t)rowSafe * Kact;
#pragma unroll
      for (int j = 0; j < 8; ++j) {
        int f = kb + j;
        float xv = 0.f;
        if (f < Kact) xv = A[f];       // exec-masked: no OOB read
        av[j] = (short)f2bf(xv);
      }
    }
    const unsigned short* bbase =
        Bt3 + (size_t)((ks * 4 + kgrp) * COLS + lc) * 8;
#pragma unroll
    for (int fc = 0; fc < CFRAGS; ++fc) {
      short8 bv = *(const short8*)(bbase + fc * 128);
      acc[fc] = __builtin_amdgcn_mfma_f32_16x16x32_bf16(av, bv, acc[fc], 0, 0, 0);
    }
  }

  if constexpr (KSPLIT > 1) {
    if (kslice > 0) {
      float* dst =
          red + (((kslice - 1) * RG + rowgrp) * 64 + l) * (CFRAGS * 4);
#pragma unroll
      for (int fc = 0; fc < CFRAGS; ++fc)
#pragma unroll
        for (int r = 0; r < 4; ++r) dst[fc * 4 + r] = acc[fc][r];
    }
    __syncthreads();
    if (kslice == 0) {
#pragma unroll
      for (int s2 = 1; s2 < KSPLIT; ++s2) {
        const float* src2 =
            red + (((s2 - 1) * RG + rowgrp) * 64 + l) * (CFRAGS * 4);
#pragma unroll
        for (int fc = 0; fc < CFRAGS; ++fc)
#pragma unroll
          for (int r = 0; r < 4; ++r) acc[fc][r] += src2[fc * 4 + r];
      }
    }
  }

  if (kslice == 0) {
#pragma unroll
    for (int fc = 0; fc < OUTFRAGS; ++fc) {
#pragma unroll
      for (int r = 0; r < 4; ++r) {
        int gr = rowD + r;
        if (gr < N) outW[(size_t)gr * H + fc * 16 + lc] = f2bf(acc[fc][r]);
      }
    }
    if (lc < 2) {
      f32x4 g = acc[CFRAGS - 1];
#pragma unroll
      for (int r = 0; r < 4; ++r) {
        int gr = rowD + r;
        if (gr < N) {
          if (lc == 0) s[gr] = 1.f / (1.f + expf(-(g[r] + sb[0])));
          else Dk[gr] = g[r] + db[0];
        }
      }
    }
  }
}

// ---------------------------------------------------------------------------
// Tile binning: bucket = dst >> 7 (128-node tiles). nb <= 512 assumed.
// All histogram/cursor atomics are INT (R5 lesson: fp32 LDS atomics = CAS
// loop = 26x slowdown).
// ---------------------------------------------------------------------------
#define BIN_CHUNK 4096

__global__ __launch_bounds__(256) void bucket_count(
    const int* __restrict__ ei, int E, int* __restrict__ bcnt) {
  __shared__ int lc[512];
  for (int i = threadIdx.x; i < 512; i += 256) lc[i] = 0;
  __syncthreads();
  const int base = blockIdx.x * BIN_CHUNK;
  for (int k = threadIdx.x; k < BIN_CHUNK; k += 256) {
    int e = base + k;
    if (e < E) atomicAdd(&lc[ei[E + e] >> 7], 1);
  }
  __syncthreads();
  for (int b = threadIdx.x; b < 512; b += 256)
    if (lc[b]) atomicAdd(&bcnt[b], lc[b]);
}

__global__ __launch_bounds__(512) void bucket_scan(
    const int* __restrict__ bcnt, int nb, int* __restrict__ boff,
    int* __restrict__ gcur) {
  __shared__ int sh[512];
  int t = threadIdx.x;
  int v = (t < nb) ? bcnt[t] : 0;
  sh[t] = v;
  __syncthreads();
  int acc = v;
  for (int off = 1; off < 512; off <<= 1) {
    int xx = (t >= off) ? sh[t - off] : 0;
    __syncthreads();
    acc += xx;
    sh[t] = acc;
    __syncthreads();
  }
  if (t < nb) {
    boff[t] = acc - v;
    gcur[t] = acc - v;
  }
  if (t == nb - 1) boff[nb] = acc;
}

__global__ __launch_bounds__(256) void bin_fill(
    const int* __restrict__ ei, const float* __restrict__ ew, int E,
    int* __restrict__ gcur, int2* __restrict__ rec) {
  __shared__ int2 se[BIN_CHUNK];
  __shared__ int scnt[512];
  __shared__ int scur[512];
  for (int i = threadIdx.x; i < 512; i += 256) scnt[i] = 0;
  __syncthreads();
  const int base = blockIdx.x * BIN_CHUNK;
  for (int k = threadIdx.x; k < BIN_CHUNK; k += 256) {
    int e = base + k;
    if (e < E) {
      int src = ei[e];
      int dst = ei[E + e];
      se[k] = make_int2(src, dst);
      atomicAdd(&scnt[dst >> 7], 1);
    }
  }
  __syncthreads();
  for (int b = threadIdx.x; b < 512; b += 256)
    if (scnt[b]) scur[b] = atomicAdd(&gcur[b], scnt[b]);
  __syncthreads();
  for (int k = threadIdx.x; k < BIN_CHUNK; k += 256) {
    int e = base + k;
    if (e < E) {
      int2 sd = se[k];
      int b = sd.y >> 7;
      int pos = atomicAdd(&scur[b], 1);
      rec[pos] = make_int2(((sd.y & 127) << 16) | sd.x, __float_as_int(ew[e]));
    }
  }
}

__global__ __launch_bounds__(256) void tile_sort(
    const int2* __restrict__ recRaw, const int* __restrict__ boff,
    int2* __restrict__ recS, int* __restrict__ rp, int N, int nb) {
  __shared__ int cnt[128];
  __shared__ int sc[128];
  __shared__ int cur[128];
  const int tile = blockIdx.x;
  const int lo = boff[tile], hi = boff[tile + 1];
  const int t = threadIdx.x;
  if (t < 128) cnt[t] = 0;
  __syncthreads();
  for (int j = lo + t; j < hi; j += 256)
    atomicAdd(&cnt[recRaw[j].x >> 16], 1);
  __syncthreads();
  if (t < 128) sc[t] = cnt[t];
  __syncthreads();
  for (int off = 1; off < 128; off <<= 1) {
    int v = 0;
    if (t < 128 && t >= off) v = sc[t - off];
    __syncthreads();
    if (t < 128) sc[t] += v;
    __syncthreads();
  }
  if (t < 128) {
    int excl = sc[t] - cnt[t];
    cur[t] = excl;
    int n = tile * 128 + t;
    if (n < N) rp[n] = lo + excl;
  }
  if (tile == nb - 1 && t == 0) rp[N] = hi;
  __syncthreads();
  for (int j = lo + t; j < hi; j += 256) {
    int2 r = recRaw[j];
    int pos = lo + atomicAdd(&cur[r.x >> 16], 1);
    recS[pos] = r;
  }
}

// ---------------------------------------------------------------------------
// Layer-0 gather: one wave per node (64 feature lanes), 16 chains.
// ---------------------------------------------------------------------------
static __device__ __forceinline__ float gather64(
    const int* __restrict__ rp, const int2* __restrict__ rec,
    const unsigned short* __restrict__ feat, int n, int h) {
  int b = rp[n], e = rp[n + 1];
  float a[16];
#pragma unroll
  for (int u = 0; u < 16; ++u) a[u] = 0.f;
  int j = b;
  for (; j + 16 <= e; j += 16) {
#pragma unroll
    for (int u = 0; u < 16; ++u) {
      int2 r = rec[j + u];
      a[u] += __int_as_float(r.y) *
              bf2f(feat[(size_t)(r.x & 0xFFFF) * 64 + h]);
    }
  }
  for (; j + 4 <= e; j += 4) {
#pragma unroll
    for (int u = 0; u < 4; ++u) {
      int2 r = rec[j + u];
      a[u] += __int_as_float(r.y) *
              bf2f(feat[(size_t)(r.x & 0xFFFF) * 64 + h]);
    }
  }
  for (; j < e; ++j) {
    int2 r = rec[j];
    a[0] += __int_as_float(r.y) * bf2f(feat[(size_t)(r.x & 0xFFFF) * 64 + h]);
  }
  float t0 = ((a[0] + a[1]) + (a[2] + a[3])) + ((a[4] + a[5]) + (a[6] + a[7]));
  float t1 = ((a[8] + a[9]) + (a[10] + a[11])) +
             ((a[12] + a[13]) + (a[14] + a[15]));
  return t0 + t1;
}

__global__ __launch_bounds__(256) void agg_combine64(
    const int* __restrict__ rpA, const int2* __restrict__ recA,
    const int* __restrict__ rpK, const int2* __restrict__ recK,
    const unsigned short* __restrict__ feat, const float* __restrict__ s,
    const float* __restrict__ Dk, unsigned short* __restrict__ outp, int N) {
  int n = __builtin_amdgcn_readfirstlane((blockIdx.x * 256 + threadIdx.x) >> 6);
  if (n >= N) return;
  int h = threadIdx.x & 63;
  float aA = gather64(rpA, recA, feat, n, h);
  float aK = gather64(rpK, recK, feat, n, h);
  float sv = s[n];
  float res = sv * aA + (1.f - sv) * aK +
              GAMMA * Dk[n] * bf2f(feat[(size_t)n * 64 + h]);
  outp[(size_t)n * 64 + h] = f2bf(res);
}

// ---------------------------------------------------------------------------
// Layer-1 gather (H=16, 4 nodes per wave): vector loads, 8 chains.
// ---------------------------------------------------------------------------
static __device__ __forceinline__ float gather16(
    const int* __restrict__ rp, const int2* __restrict__ rec,
    const unsigned short* __restrict__ feat, int n, int h) {
  int b = rp[n], e = rp[n + 1];
  float a0 = 0.f, a1 = 0.f, a2 = 0.f, a3 = 0.f;
  float a4 = 0.f, a5 = 0.f, a6 = 0.f, a7 = 0.f;
  const long long* recq = (const long long*)rec;
  int j = b;
  for (; j + 8 <= e; j += 8) {
    long long q0 = __builtin_nontemporal_load(recq + j + 0);
    long long q1 = __builtin_nontemporal_load(recq + j + 1);
    long long q2 = __builtin_nontemporal_load(recq + j + 2);
    long long q3 = __builtin_nontemporal_load(recq + j + 3);
    long long q4 = __builtin_nontemporal_load(recq + j + 4);
    long long q5 = __builtin_nontemporal_load(recq + j + 5);
    long long q6 = __builtin_nontemporal_load(recq + j + 6);
    long long q7 = __builtin_nontemporal_load(recq + j + 7);
    a0 += __int_as_float((int)(q0 >> 32)) *
          bf2f(feat[(size_t)(q0 & 0xFFFF) * 16 + h]);
    a1 += __int_as_float((int)(q1 >> 32)) *
          bf2f(feat[(size_t)(q1 & 0xFFFF) * 16 + h]);
    a2 += __int_as_float((int)(q2 >> 32)) *
          bf2f(feat[(size_t)(q2 & 0xFFFF) * 16 + h]);
    a3 += __int_as_float((int)(q3 >> 32)) *
          bf2f(feat[(size_t)(q3 & 0xFFFF) * 16 + h]);
    a4 += __int_as_float((int)(q4 >> 32)) *
          bf2f(feat[(size_t)(q4 & 0xFFFF) * 16 + h]);
    a5 += __int_as_float((int)(q5 >> 32)) *
          bf2f(feat[(size_t)(q5 & 0xFFFF) * 16 + h]);
    a6 += __int_as_float((int)(q6 >> 32)) *
          bf2f(feat[(size_t)(q6 & 0xFFFF) * 16 + h]);
    a7 += __int_as_float((int)(q7 >> 32)) *
          bf2f(feat[(size_t)(q7 & 0xFFFF) * 16 + h]);
  }
  for (; j < e; ++j) {
    long long q = __builtin_nontemporal_load(recq + j);
    a0 += __int_as_float((int)(q >> 32)) *
          bf2f(feat[(size_t)(q & 0xFFFF) * 16 + h]);
  }
  return ((a0 + a1) + (a2 + a3)) + ((a4 + a5) + (a6 + a7));
}

__global__ __launch_bounds__(256) void agg_combine16(
    const int* __restrict__ rpA, const int2* __restrict__ recA,
    const int* __restrict__ rpK, const int2* __restrict__ recK,
    const unsigned short* __restrict__ feat, const float* __restrict__ s,
    const float* __restrict__ Dk, float* __restrict__ outp, int N) {
  int tid = blockIdx.x * 256 + threadIdx.x;
  int n = tid >> 4;
  int h = tid & 15;
  if (n >= N) return;
  float aA = gather16(rpA, recA, feat, n, h);
  float aK = gather16(rpK, recK, feat, n, h);
  float sv = s[n];
  float res = sv * aA + (1.f - sv) * aK +
              GAMMA * Dk[n] * bf2f(feat[(size_t)n * 16 + h]);
  outp[(size_t)n * 16 + h] = res;
}

// ---------------------------------------------------------------------------
extern "C" void kernel_launch(void* const* d_in, const int* in_sizes, int n_in,
                              void* d_out, int out_size, void* d_ws, size_t ws_size,
                              hipStream_t stream) {
  const float* x = (const float*)d_in[0];
  const int* edge_index = (const int*)d_in[1];
  const float* edge_weight = (const float*)d_in[2];
  const int* knn_edge_index = (const int*)d_in[3];
  const float* knn_edge_weight = (const float*)d_in[4];
  const float* W0 = (const float*)d_in[5];
  const float* W1 = (const float*)d_in[6];
  const float* score0 = (const float*)d_in[7];
  const float* sbias0 = (const float*)d_in[8];
  const float* score1 = (const float*)d_in[9];
  const float* sbias1 = (const float*)d_in[10];
  const float* Dk0 = (const float*)d_in[11];
  const float* Dbias0 = (const float*)d_in[12];
  const float* Dk1 = (const float*)d_in[13];
  const float* Dbias1 = (const float*)d_in[14];

  const int F = in_sizes[7];          // 500
  const int N = in_sizes[0] / F;      // 50000 (< 65536: src packed in 16 bits)
  const int E = in_sizes[2];          // 1.6M
  const int Ek = in_sizes[4];         // 1.0M
  (void)n_in; (void)ws_size; (void)out_size;

  const int nb = (N + 127) / 128;     // 391 dst tiles (<= 512)

  // ---- workspace bump allocator (256B-aligned slices) ----
  char* cur = (char*)d_ws;
  auto alloc = [&](size_t bytes) {
    char* p = cur;
    cur += (bytes + 255) & ~(size_t)255;
    return (void*)p;
  };
  float* sbuf = (float*)alloc((size_t)N * 4);
  float* dkbuf = (float*)alloc((size_t)N * 4);
  int* bcnt2 = (int*)alloc((size_t)2 * nb * 4);   // ONE slice: memset covers both
  int* bcntA = bcnt2;
  int* bcntK = bcnt2 + nb;
  int* boffA = (int*)alloc((size_t)(nb + 1) * 4);
  int* boffK = (int*)alloc((size_t)(nb + 1) * 4);
  int* gcurA = (int*)alloc((size_t)nb * 4);
  int* gcurK = (int*)alloc((size_t)nb * 4);
  int* rpA = (int*)alloc((size_t)(N + 1) * 4);
  int* rpK = (int*)alloc((size_t)(N + 1) * 4);
  int2* recA = (int2*)alloc((size_t)E * 8);       // sorted (exact CSR)
  int2* recK = (int2*)alloc((size_t)Ek * 8);
  unsigned short* Bt0 = (unsigned short*)alloc((size_t)80 * 512 * 2);
  unsigned short* Bt1 = (unsigned short*)alloc((size_t)32 * 64 * 2);
  // UNION region: recRaw (dead after tile_sort) overlaps the feature buffers
  // (written only after tile_sort completes; same stream => safe).
  char* uni = (char*)alloc((size_t)(E + Ek) * 8);
  int2* recRawA = (int2*)uni;
  int2* recRawK = recRawA + E;
  unsigned short* xWb = (unsigned short*)uni;              // N*64
  unsigned short* x1b = xWb + (size_t)N * 64;              // N*64
  unsigned short* xW1b = x1b + (size_t)N * 64;             // N*16

  // ---- B transposes (tiny), K-chunk-major ----
  build_bt3<<<(80 * 512 + 255) / 256, 256, 0, stream>>>(W0, score0, Dk0, Bt0,
                                                        64, F, 512, 80);
  build_bt3<<<(32 * 64 + 255) / 256, 256, 0, stream>>>(W1, score1, Dk1, Bt1,
                                                       16, 64, 64, 32);

  // ---- tile binning + exact CSR (reused by both layers) ----
  hipMemsetAsync(bcnt2, 0, (size_t)2 * nb * sizeof(int), stream);
  const int nchA = (E + BIN_CHUNK - 1) / BIN_CHUNK;
  const int nchK = (Ek + BIN_CHUNK - 1) / BIN_CHUNK;
  bucket_count<<<nchA, 256, 0, stream>>>(edge_index, E, bcntA);
  bucket_count<<<nchK, 256, 0, stream>>>(knn_edge_index, Ek, bcntK);
  bucket_scan<<<1, 512, 0, stream>>>(bcntA, nb, boffA, gcurA);
  bucket_scan<<<1, 512, 0, stream>>>(bcntK, nb, boffK, gcurK);
  bin_fill<<<nchA, 256, 0, stream>>>(edge_index, edge_weight, E, gcurA,
                                     recRawA);
  bin_fill<<<nchK, 256, 0, stream>>>(knn_edge_index, knn_edge_weight, Ek,
                                     gcurK, recRawK);
  tile_sort<<<nb, 256, 0, stream>>>(recRawA, boffA, recA, rpA, N, nb);
  tile_sort<<<nb, 256, 0, stream>>>(recRawK, boffK, recK, rpK, N, nb);

  const int gemmBlocks = (N + 31) / 32;           // 32 rows/block (K-split 2)
  const int agg64Blocks = (int)(((size_t)N * 64 + 255) / 256);
  const int agg16Blocks = (int)(((size_t)N * 16 + 255) / 256);

  // ---- Layer 0: F=500 -> H=64 (+gate+Dk) ----
  mfma_linear<512, 5, 4, false, 2, 80><<<gemmBlocks, 256, 0, stream>>>(
      x, Bt0, sbias0, Dbias0, xWb, sbuf, dkbuf, N, F);
  agg_combine64<<<agg64Blocks, 256, 0, stream>>>(rpA, recA, rpK, recK, xWb,
                                                 sbuf, dkbuf, x1b, N);

  // ---- Layer 1: H=64 -> O=16 (+gate+Dk) ----
  mfma_linear<64, 2, 1, true, 2, 32><<<gemmBlocks, 256, 0, stream>>>(
      x1b, Bt1, sbias1, Dbias1, xW1b, sbuf, dkbuf, N, 64);
  agg_combine16<<<agg16Blocks, 256, 0, stream>>>(rpA, recA, rpK, recK, xW1b,
                                                 sbuf, dkbuf, (float*)d_out, N);
}

// Round 12
// 220.070 us; speedup vs baseline: 1.5516x; 1.0837x over previous
//
#include <hip/hip_runtime.h>
#include <math.h>

#define GAMMA 0.1f

typedef float f32x4 __attribute__((ext_vector_type(4)));
typedef short short4v __attribute__((ext_vector_type(4)));
typedef short short8 __attribute__((ext_vector_type(8)));

static __device__ __forceinline__ unsigned short f2bf(float f) {
  union { float f; unsigned u; } v; v.f = f;
  unsigned r = v.u + 0x7FFF + ((v.u >> 16) & 1);   // RNE
  return (unsigned short)(r >> 16);
}
static __device__ __forceinline__ float bf2f(unsigned short b) {
  union { unsigned u; float f; } v; v.u = ((unsigned)b) << 16;
  return v.f;
}

// ---------------------------------------------------------------------------
// Build K-chunk-major bf16 B: entry (k/8)*COLS + c holds Bt[c][k8..k8+8).
//   c < H : W[k][c];  c == H : sc[k];  c == H+1 : dk[k];  else/k>=Kact : 0
// ---------------------------------------------------------------------------
__global__ __launch_bounds__(256) void build_bt3(
    const float* __restrict__ W, const float* __restrict__ sc,
    const float* __restrict__ dk, unsigned short* __restrict__ Bt3,
    int H, int Kact, int KPAD, int COLS) {
  int i = blockIdx.x * 256 + threadIdx.x;
  if (i >= COLS * KPAD) return;
  int c = i / KPAD;
  int k = i - c * KPAD;
  float v = 0.f;
  if (k < Kact) {
    if (c < H) v = W[(size_t)k * H + c];
    else if (c == H) v = sc[k];
    else if (c == H + 1) v = dk[k];
  }
  Bt3[(size_t)((k >> 3) * COLS + c) * 8 + (k & 7)] = f2bf(v);
}

// ---------------------------------------------------------------------------
// Layer-0 fused MFMA linear with LDS-staged A.
// Block = 32 rows. Staging: coalesced f32x4 row-major loads -> bf16 ->
// XOR-swizzled LDS (byte ^= (row&7)<<4) so fragment ds_read_b128 at 1KB row
// stride is 2-way (free) instead of 16-way conflicted (T2/G4).
// 4 waves = 2 row-groups x 2 K-slices; LDS reduction; kslice 0 epilogue.
// ---------------------------------------------------------------------------
template <int CFRAGS, int OUTFRAGS, int COLS>
__global__ __launch_bounds__(256) void mfma_linear_l0(
    const float* __restrict__ A, const unsigned short* __restrict__ Bt3,
    const float* __restrict__ sb, const float* __restrict__ db,
    unsigned short* __restrict__ outW, float* __restrict__ s,
    float* __restrict__ Dk, int N, int Kact) {
  constexpr int KPAD = 512;
  constexpr int KSPLIT = 2, RG = 2, RPB = 32;
  constexpr int KS_PER = (KPAD / 32) / KSPLIT;     // 8
  constexpr int H = OUTFRAGS * 16;
  __shared__ unsigned short Ald[RPB * KPAD];       // 32 KB, swizzled
  __shared__ float red[(KSPLIT - 1) * RG * 64 * CFRAGS * 4];  // 10 KB

  const int t = threadIdx.x;
  const int rowBase = blockIdx.x * RPB;

  // ---- stage A (16 iters, 256 thr x f32x4, lane-consecutive = coalesced) --
#pragma unroll
  for (int it = 0; it < (RPB * KPAD) / (256 * 4); ++it) {
    int li = it * 1024 + t * 4;        // linear f32 idx in [32][512]
    int row = li >> 9;
    int col = li & 511;
    int grow = rowBase + row;
    f32x4 v = (f32x4)0.f;
    if (grow < N && col < Kact)        // col%4==0, col<=496 -> col+3<500 ok
      v = *(const f32x4*)(A + (size_t)grow * Kact + col);
    short4v b;
#pragma unroll
    for (int j = 0; j < 4; ++j) b[j] = (short)f2bf(v[j]);
    int byte = row * (KPAD * 2) + ((col * 2) ^ ((row & 7) << 4));
    *(short4v*)((char*)Ald + byte) = b;
  }
  __syncthreads();

  const int w = t >> 6;
  const int rowgrp = w % RG;
  const int kslice = w / RG;
  const int l = t & 63;
  const int kgrp = l >> 4;
  const int lc = l & 15;
  const int lrow = rowgrp * 16 + lc;                 // local A row
  const int rowD = rowBase + rowgrp * 16 + kgrp * 4; // D rows base

  f32x4 acc[CFRAGS];
#pragma unroll
  for (int i = 0; i < CFRAGS; ++i) acc[i] = (f32x4)0.f;

  const int rbyte = lrow * (KPAD * 2);
  const int rswz = (lrow & 7) << 4;
#pragma unroll
  for (int kk = 0; kk < KS_PER; ++kk) {
    const int ks = kslice * KS_PER + kk;
    short8 av = *(const short8*)((char*)Ald +
                                 (rbyte + ((ks * 64 + kgrp * 16) ^ rswz)));
    const unsigned short* bbase =
        Bt3 + (size_t)((ks * 4 + kgrp) * COLS + lc) * 8;
#pragma unroll
    for (int fc = 0; fc < CFRAGS; ++fc) {
      short8 bv = *(const short8*)(bbase + fc * 128);
      acc[fc] = __builtin_amdgcn_mfma_f32_16x16x32_bf16(av, bv, acc[fc], 0, 0, 0);
    }
  }

  // ---- K-split reduction ----
  if (kslice > 0) {
    float* dst = red + ((rowgrp)*64 + l) * (CFRAGS * 4);
#pragma unroll
    for (int fc = 0; fc < CFRAGS; ++fc)
#pragma unroll
      for (int r = 0; r < 4; ++r) dst[fc * 4 + r] = acc[fc][r];
  }
  __syncthreads();
  if (kslice == 0) {
    const float* src2 = red + ((rowgrp)*64 + l) * (CFRAGS * 4);
#pragma unroll
    for (int fc = 0; fc < CFRAGS; ++fc)
#pragma unroll
      for (int r = 0; r < 4; ++r) acc[fc][r] += src2[fc * 4 + r];

    // ---- epilogue ----
#pragma unroll
    for (int fc = 0; fc < OUTFRAGS; ++fc) {
#pragma unroll
      for (int r = 0; r < 4; ++r) {
        int gr = rowD + r;
        if (gr < N) outW[(size_t)gr * H + fc * 16 + lc] = f2bf(acc[fc][r]);
      }
    }
    if (lc < 2) {
      f32x4 g = acc[CFRAGS - 1];
#pragma unroll
      for (int r = 0; r < 4; ++r) {
        int gr = rowD + r;
        if (gr < N) {
          if (lc == 0) s[gr] = 1.f / (1.f + expf(-(g[r] + sb[0])));
          else Dk[gr] = g[r] + db[0];
        }
      }
    }
  }
}

// ---------------------------------------------------------------------------
// Layer-1 fused MFMA linear (bf16 A, K=64): A loads already line-efficient.
// 4 waves = 2 row-groups x 2 K-slices (R10/R11 structure, unchanged).
// ---------------------------------------------------------------------------
template <int KPAD, int CFRAGS, int OUTFRAGS, int COLS>
__global__ __launch_bounds__(256) void mfma_linear_bf(
    const unsigned short* __restrict__ Aptr, const unsigned short* __restrict__ Bt3,
    const float* __restrict__ sb, const float* __restrict__ db,
    unsigned short* __restrict__ outW, float* __restrict__ s,
    float* __restrict__ Dk, int N, int Kact) {
  constexpr int H = OUTFRAGS * 16;
  constexpr int KSPLIT = 2, RG = 2, RPB = 32;
  constexpr int KS_PER = (KPAD / 32) / KSPLIT;
  __shared__ float red[(KSPLIT - 1) * RG * 64 * CFRAGS * 4];

  const int w = threadIdx.x >> 6;
  const int rowgrp = w % RG;
  const int kslice = w / RG;
  const int l = threadIdx.x & 63;
  const int kgrp = l >> 4;
  const int lc = l & 15;
  const int rowA = blockIdx.x * RPB + rowgrp * 16 + lc;
  const int rowD = blockIdx.x * RPB + rowgrp * 16 + kgrp * 4;
  const int rowSafe = (rowA < N) ? rowA : 0;

  f32x4 acc[CFRAGS];
#pragma unroll
  for (int i = 0; i < CFRAGS; ++i) acc[i] = (f32x4)0.f;

#pragma unroll
  for (int kk = 0; kk < KS_PER; ++kk) {
    const int ks = kslice * KS_PER + kk;
    const int kb = ks * 32 + kgrp * 8;
    short8 av = *(const short8*)(Aptr + (size_t)rowSafe * Kact + kb);
    const unsigned short* bbase =
        Bt3 + (size_t)((ks * 4 + kgrp) * COLS + lc) * 8;
#pragma unroll
    for (int fc = 0; fc < CFRAGS; ++fc) {
      short8 bv = *(const short8*)(bbase + fc * 128);
      acc[fc] = __builtin_amdgcn_mfma_f32_16x16x32_bf16(av, bv, acc[fc], 0, 0, 0);
    }
  }

  if (kslice > 0) {
    float* dst = red + ((rowgrp)*64 + l) * (CFRAGS * 4);
#pragma unroll
    for (int fc = 0; fc < CFRAGS; ++fc)
#pragma unroll
      for (int r = 0; r < 4; ++r) dst[fc * 4 + r] = acc[fc][r];
  }
  __syncthreads();
  if (kslice == 0) {
    const float* src2 = red + ((rowgrp)*64 + l) * (CFRAGS * 4);
#pragma unroll
    for (int fc = 0; fc < CFRAGS; ++fc)
#pragma unroll
      for (int r = 0; r < 4; ++r) acc[fc][r] += src2[fc * 4 + r];

#pragma unroll
    for (int fc = 0; fc < OUTFRAGS; ++fc) {
#pragma unroll
      for (int r = 0; r < 4; ++r) {
        int gr = rowD + r;
        if (gr < N) outW[(size_t)gr * H + fc * 16 + lc] = f2bf(acc[fc][r]);
      }
    }
    if (lc < 2) {
      f32x4 g = acc[CFRAGS - 1];
#pragma unroll
      for (int r = 0; r < 4; ++r) {
        int gr = rowD + r;
        if (gr < N) {
          if (lc == 0) s[gr] = 1.f / (1.f + expf(-(g[r] + sb[0])));
          else Dk[gr] = g[r] + db[0];
        }
      }
    }
  }
}

// ---------------------------------------------------------------------------
// Tile binning, A+K fused per kernel (halves serialized launches).
// bucket = dst >> 7 (128-node tiles). INT atomics only (R5 lesson).
// ---------------------------------------------------------------------------
#define BIN_CHUNK 4096

__global__ __launch_bounds__(256) void bucket_count2(
    const int* __restrict__ eiA, int EA, int* __restrict__ bcntA,
    const int* __restrict__ eiK, int EK, int* __restrict__ bcntK, int nchA) {
  const int* ei;
  int E, chunk;
  int* bcnt;
  if (blockIdx.x < nchA) { ei = eiA; E = EA; bcnt = bcntA; chunk = blockIdx.x; }
  else { ei = eiK; E = EK; bcnt = bcntK; chunk = blockIdx.x - nchA; }
  __shared__ int lc[512];
  for (int i = threadIdx.x; i < 512; i += 256) lc[i] = 0;
  __syncthreads();
  const int base = chunk * BIN_CHUNK;
  for (int k = threadIdx.x; k < BIN_CHUNK; k += 256) {
    int e = base + k;
    if (e < E) atomicAdd(&lc[ei[E + e] >> 7], 1);
  }
  __syncthreads();
  for (int b = threadIdx.x; b < 512; b += 256)
    if (lc[b]) atomicAdd(&bcnt[b], lc[b]);
}

// 2 blocks: block 0 scans A counts, block 1 scans K counts.
__global__ __launch_bounds__(512) void bucket_scan2(
    int* __restrict__ bcntA, int* __restrict__ boffA, int* __restrict__ gcurA,
    int* __restrict__ bcntK, int* __restrict__ boffK, int* __restrict__ gcurK,
    int nb) {
  int* bcnt = blockIdx.x ? bcntK : bcntA;
  int* boff = blockIdx.x ? boffK : boffA;
  int* gcur = blockIdx.x ? gcurK : gcurA;
  __shared__ int sh[512];
  int t = threadIdx.x;
  int v = (t < nb) ? bcnt[t] : 0;
  sh[t] = v;
  __syncthreads();
  int acc = v;
  for (int off = 1; off < 512; off <<= 1) {
    int xx = (t >= off) ? sh[t - off] : 0;
    __syncthreads();
    acc += xx;
    sh[t] = acc;
    __syncthreads();
  }
  if (t < nb) {
    boff[t] = acc - v;
    gcur[t] = acc - v;
  }
  if (t == nb - 1) boff[nb] = acc;
}

__global__ __launch_bounds__(256) void bin_fill2(
    const int* __restrict__ eiA, const float* __restrict__ ewA, int EA,
    int* __restrict__ gcurA, int2* __restrict__ recA,
    const int* __restrict__ eiK, const float* __restrict__ ewK, int EK,
    int* __restrict__ gcurK, int2* __restrict__ recK, int nchA) {
  const int* ei;
  const float* ew;
  int E, chunk;
  int* gcur;
  int2* rec;
  if (blockIdx.x < nchA) {
    ei = eiA; ew = ewA; E = EA; gcur = gcurA; rec = recA; chunk = blockIdx.x;
  } else {
    ei = eiK; ew = ewK; E = EK; gcur = gcurK; rec = recK;
    chunk = blockIdx.x - nchA;
  }
  __shared__ int2 se[BIN_CHUNK];
  __shared__ int scnt[512];
  __shared__ int scur[512];
  for (int i = threadIdx.x; i < 512; i += 256) scnt[i] = 0;
  __syncthreads();
  const int base = chunk * BIN_CHUNK;
  for (int k = threadIdx.x; k < BIN_CHUNK; k += 256) {
    int e = base + k;
    if (e < E) {
      int src = ei[e];
      int dst = ei[E + e];
      se[k] = make_int2(src, dst);
      atomicAdd(&scnt[dst >> 7], 1);
    }
  }
  __syncthreads();
  for (int b = threadIdx.x; b < 512; b += 256)
    if (scnt[b]) scur[b] = atomicAdd(&gcur[b], scnt[b]);
  __syncthreads();
  for (int k = threadIdx.x; k < BIN_CHUNK; k += 256) {
    int e = base + k;
    if (e < E) {
      int2 sd = se[k];
      int b = sd.y >> 7;
      int pos = atomicAdd(&scur[b], 1);
      rec[pos] = make_int2(((sd.y & 127) << 16) | sd.x, __float_as_int(ew[e]));
    }
  }
}

__global__ __launch_bounds__(256) void tile_sort2(
    const int2* __restrict__ recRawA, const int* __restrict__ boffA,
    int2* __restrict__ recSA, int* __restrict__ rpA,
    const int2* __restrict__ recRawK, const int* __restrict__ boffK,
    int2* __restrict__ recSK, int* __restrict__ rpK, int N, int nb) {
  const int2* recRaw;
  const int* boff;
  int2* recS;
  int* rp;
  int tile;
  if (blockIdx.x < nb) {
    recRaw = recRawA; boff = boffA; recS = recSA; rp = rpA; tile = blockIdx.x;
  } else {
    recRaw = recRawK; boff = boffK; recS = recSK; rp = rpK;
    tile = blockIdx.x - nb;
  }
  __shared__ int cnt[128];
  __shared__ int sc[128];
  __shared__ int cur[128];
  const int lo = boff[tile], hi = boff[tile + 1];
  const int t = threadIdx.x;
  if (t < 128) cnt[t] = 0;
  __syncthreads();
  for (int j = lo + t; j < hi; j += 256)
    atomicAdd(&cnt[recRaw[j].x >> 16], 1);
  __syncthreads();
  if (t < 128) sc[t] = cnt[t];
  __syncthreads();
  for (int off = 1; off < 128; off <<= 1) {
    int v = 0;
    if (t < 128 && t >= off) v = sc[t - off];
    __syncthreads();
    if (t < 128) sc[t] += v;
    __syncthreads();
  }
  if (t < 128) {
    int excl = sc[t] - cnt[t];
    cur[t] = excl;
    int n = tile * 128 + t;
    if (n < N) rp[n] = lo + excl;
  }
  if (tile == nb - 1 && t == 0) rp[N] = hi;
  __syncthreads();
  for (int j = lo + t; j < hi; j += 256) {
    int2 r = recRaw[j];
    int pos = lo + atomicAdd(&cur[r.x >> 16], 1);
    recS[pos] = r;
  }
}

// ---------------------------------------------------------------------------
// Layer-0 gather: one wave per node (64 feature lanes), 16 chains.
// ---------------------------------------------------------------------------
static __device__ __forceinline__ float gather64(
    const int* __restrict__ rp, const int2* __restrict__ rec,
    const unsigned short* __restrict__ feat, int n, int h) {
  int b = rp[n], e = rp[n + 1];
  float a[16];
#pragma unroll
  for (int u = 0; u < 16; ++u) a[u] = 0.f;
  int j = b;
  for (; j + 16 <= e; j += 16) {
#pragma unroll
    for (int u = 0; u < 16; ++u) {
      int2 r = rec[j + u];
      a[u] += __int_as_float(r.y) *
              bf2f(feat[(size_t)(r.x & 0xFFFF) * 64 + h]);
    }
  }
  for (; j + 4 <= e; j += 4) {
#pragma unroll
    for (int u = 0; u < 4; ++u) {
      int2 r = rec[j + u];
      a[u] += __int_as_float(r.y) *
              bf2f(feat[(size_t)(r.x & 0xFFFF) * 64 + h]);
    }
  }
  for (; j < e; ++j) {
    int2 r = rec[j];
    a[0] += __int_as_float(r.y) * bf2f(feat[(size_t)(r.x & 0xFFFF) * 64 + h]);
  }
  float t0 = ((a[0] + a[1]) + (a[2] + a[3])) + ((a[4] + a[5]) + (a[6] + a[7]));
  float t1 = ((a[8] + a[9]) + (a[10] + a[11])) +
             ((a[12] + a[13]) + (a[14] + a[15]));
  return t0 + t1;
}

__global__ __launch_bounds__(256) void agg_combine64(
    const int* __restrict__ rpA, const int2* __restrict__ recA,
    const int* __restrict__ rpK, const int2* __restrict__ recK,
    const unsigned short* __restrict__ feat, const float* __restrict__ s,
    const float* __restrict__ Dk, unsigned short* __restrict__ outp, int N) {
  int n = __builtin_amdgcn_readfirstlane((blockIdx.x * 256 + threadIdx.x) >> 6);
  if (n >= N) return;
  int h = threadIdx.x & 63;
  float aA = gather64(rpA, recA, feat, n, h);
  float aK = gather64(rpK, recK, feat, n, h);
  float sv = s[n];
  float res = sv * aA + (1.f - sv) * aK +
              GAMMA * Dk[n] * bf2f(feat[(size_t)n * 64 + h]);
  outp[(size_t)n * 64 + h] = f2bf(res);
}

// ---------------------------------------------------------------------------
// Layer-1 gather (H=16, 4 nodes per wave): vector loads, 8 chains.
// ---------------------------------------------------------------------------
static __device__ __forceinline__ float gather16(
    const int* __restrict__ rp, const int2* __restrict__ rec,
    const unsigned short* __restrict__ feat, int n, int h) {
  int b = rp[n], e = rp[n + 1];
  float a0 = 0.f, a1 = 0.f, a2 = 0.f, a3 = 0.f;
  float a4 = 0.f, a5 = 0.f, a6 = 0.f, a7 = 0.f;
  const long long* recq = (const long long*)rec;
  int j = b;
  for (; j + 8 <= e; j += 8) {
    long long q0 = __builtin_nontemporal_load(recq + j + 0);
    long long q1 = __builtin_nontemporal_load(recq + j + 1);
    long long q2 = __builtin_nontemporal_load(recq + j + 2);
    long long q3 = __builtin_nontemporal_load(recq + j + 3);
    long long q4 = __builtin_nontemporal_load(recq + j + 4);
    long long q5 = __builtin_nontemporal_load(recq + j + 5);
    long long q6 = __builtin_nontemporal_load(recq + j + 6);
    long long q7 = __builtin_nontemporal_load(recq + j + 7);
    a0 += __int_as_float((int)(q0 >> 32)) *
          bf2f(feat[(size_t)(q0 & 0xFFFF) * 16 + h]);
    a1 += __int_as_float((int)(q1 >> 32)) *
          bf2f(feat[(size_t)(q1 & 0xFFFF) * 16 + h]);
    a2 += __int_as_float((int)(q2 >> 32)) *
          bf2f(feat[(size_t)(q2 & 0xFFFF) * 16 + h]);
    a3 += __int_as_float((int)(q3 >> 32)) *
          bf2f(feat[(size_t)(q3 & 0xFFFF) * 16 + h]);
    a4 += __int_as_float((int)(q4 >> 32)) *
          bf2f(feat[(size_t)(q4 & 0xFFFF) * 16 + h]);
    a5 += __int_as_float((int)(q5 >> 32)) *
          bf2f(feat[(size_t)(q5 & 0xFFFF) * 16 + h]);
    a6 += __int_as_float((int)(q6 >> 32)) *
          bf2f(feat[(size_t)(q6 & 0xFFFF) * 16 + h]);
    a7 += __int_as_float((int)(q7 >> 32)) *
          bf2f(feat[(size_t)(q7 & 0xFFFF) * 16 + h]);
  }
  for (; j < e; ++j) {
    long long q = __builtin_nontemporal_load(recq + j);
    a0 += __int_as_float((int)(q >> 32)) *
          bf2f(feat[(size_t)(q & 0xFFFF) * 16 + h]);
  }
  return ((a0 + a1) + (a2 + a3)) + ((a4 + a5) + (a6 + a7));
}

__global__ __launch_bounds__(256) void agg_combine16(
    const int* __restrict__ rpA, const int2* __restrict__ recA,
    const int* __restrict__ rpK, const int2* __restrict__ recK,
    const unsigned short* __restrict__ feat, const float* __restrict__ s,
    const float* __restrict__ Dk, float* __restrict__ outp, int N) {
  int tid = blockIdx.x * 256 + threadIdx.x;
  int n = tid >> 4;
  int h = tid & 15;
  if (n >= N) return;
  float aA = gather16(rpA, recA, feat, n, h);
  float aK = gather16(rpK, recK, feat, n, h);
  float sv = s[n];
  float res = sv * aA + (1.f - sv) * aK +
              GAMMA * Dk[n] * bf2f(feat[(size_t)n * 16 + h]);
  outp[(size_t)n * 16 + h] = res;
}

// ---------------------------------------------------------------------------
extern "C" void kernel_launch(void* const* d_in, const int* in_sizes, int n_in,
                              void* d_out, int out_size, void* d_ws, size_t ws_size,
                              hipStream_t stream) {
  const float* x = (const float*)d_in[0];
  const int* edge_index = (const int*)d_in[1];
  const float* edge_weight = (const float*)d_in[2];
  const int* knn_edge_index = (const int*)d_in[3];
  const float* knn_edge_weight = (const float*)d_in[4];
  const float* W0 = (const float*)d_in[5];
  const float* W1 = (const float*)d_in[6];
  const float* score0 = (const float*)d_in[7];
  const float* sbias0 = (const float*)d_in[8];
  const float* score1 = (const float*)d_in[9];
  const float* sbias1 = (const float*)d_in[10];
  const float* Dk0 = (const float*)d_in[11];
  const float* Dbias0 = (const float*)d_in[12];
  const float* Dk1 = (const float*)d_in[13];
  const float* Dbias1 = (const float*)d_in[14];

  const int F = in_sizes[7];          // 500
  const int N = in_sizes[0] / F;      // 50000 (< 65536: src packed in 16 bits)
  const int E = in_sizes[2];          // 1.6M
  const int Ek = in_sizes[4];         // 1.0M
  (void)n_in; (void)ws_size; (void)out_size;

  const int nb = (N + 127) / 128;     // 391 dst tiles (<= 512)

  // ---- workspace bump allocator (256B-aligned slices) ----
  char* cur = (char*)d_ws;
  auto alloc = [&](size_t bytes) {
    char* p = cur;
    cur += (bytes + 255) & ~(size_t)255;
    return (void*)p;
  };
  float* sbuf = (float*)alloc((size_t)N * 4);
  float* dkbuf = (float*)alloc((size_t)N * 4);
  int* bcnt2 = (int*)alloc((size_t)2 * nb * 4);   // ONE slice: memset covers both
  int* bcntA = bcnt2;
  int* bcntK = bcnt2 + nb;
  int* boffA = (int*)alloc((size_t)(nb + 1) * 4);
  int* boffK = (int*)alloc((size_t)(nb + 1) * 4);
  int* gcurA = (int*)alloc((size_t)nb * 4);
  int* gcurK = (int*)alloc((size_t)nb * 4);
  int* rpA = (int*)alloc((size_t)(N + 1) * 4);
  int* rpK = (int*)alloc((size_t)(N + 1) * 4);
  int2* recA = (int2*)alloc((size_t)E * 8);       // sorted (exact CSR)
  int2* recK = (int2*)alloc((size_t)Ek * 8);
  unsigned short* Bt0 = (unsigned short*)alloc((size_t)80 * 512 * 2);
  unsigned short* Bt1 = (unsigned short*)alloc((size_t)32 * 64 * 2);
  // UNION region: recRaw (dead after tile_sort) overlaps the feature buffers
  // (written only after tile_sort completes; same stream => safe).
  char* uni = (char*)alloc((size_t)(E + Ek) * 8);
  int2* recRawA = (int2*)uni;
  int2* recRawK = recRawA + E;
  unsigned short* xWb = (unsigned short*)uni;              // N*64
  unsigned short* x1b = xWb + (size_t)N * 64;              // N*64
  unsigned short* xW1b = x1b + (size_t)N * 64;             // N*16

  // ---- B transposes (tiny), K-chunk-major ----
  build_bt3<<<(80 * 512 + 255) / 256, 256, 0, stream>>>(W0, score0, Dk0, Bt0,
                                                        64, F, 512, 80);
  build_bt3<<<(32 * 64 + 255) / 256, 256, 0, stream>>>(W1, score1, Dk1, Bt1,
                                                       16, 64, 64, 32);

  // ---- tile binning + exact CSR (A+K fused per stage) ----
  hipMemsetAsync(bcnt2, 0, (size_t)2 * nb * sizeof(int), stream);
  const int nchA = (E + BIN_CHUNK - 1) / BIN_CHUNK;
  const int nchK = (Ek + BIN_CHUNK - 1) / BIN_CHUNK;
  bucket_count2<<<nchA + nchK, 256, 0, stream>>>(edge_index, E, bcntA,
                                                 knn_edge_index, Ek, bcntK,
                                                 nchA);
  bucket_scan2<<<2, 512, 0, stream>>>(bcntA, boffA, gcurA, bcntK, boffK,
                                      gcurK, nb);
  bin_fill2<<<nchA + nchK, 256, 0, stream>>>(edge_index, edge_weight, E,
                                             gcurA, recRawA, knn_edge_index,
                                             knn_edge_weight, Ek, gcurK,
                                             recRawK, nchA);
  tile_sort2<<<2 * nb, 256, 0, stream>>>(recRawA, boffA, recA, rpA, recRawK,
                                         boffK, recK, rpK, N, nb);

  const int gemmBlocks = (N + 31) / 32;           // 32 rows/block
  const int agg64Blocks = (int)(((size_t)N * 64 + 255) / 256);
  const int agg16Blocks = (int)(((size_t)N * 16 + 255) / 256);

  // ---- Layer 0: F=500 -> H=64 (+gate+Dk), LDS-staged A ----
  mfma_linear_l0<5, 4, 80><<<gemmBlocks, 256, 0, stream>>>(
      x, Bt0, sbias0, Dbias0, xWb, sbuf, dkbuf, N, F);
  agg_combine64<<<agg64Blocks, 256, 0, stream>>>(rpA, recA, rpK, recK, xWb,
                                                 sbuf, dkbuf, x1b, N);

  // ---- Layer 1: H=64 -> O=16 (+gate+Dk) ----
  mfma_linear_bf<64, 2, 1, 32><<<gemmBlocks, 256, 0, stream>>>(
      x1b, Bt1, sbias1, Dbias1, xW1b, sbuf, dkbuf, N, 64);
  agg_combine16<<<agg16Blocks, 256, 0, stream>>>(rpA, recA, rpK, recK, xW1b,
                                                 sbuf, dkbuf, (float*)d_out, N);
}

// Round 13
// 202.629 us; speedup vs baseline: 1.6851x; 1.0861x over previous
//
#include <hip/hip_runtime.h>
#include <math.h>

#define GAMMA 0.1f

typedef float f32x4 __attribute__((ext_vector_type(4)));
typedef short short4v __attribute__((ext_vector_type(4)));
typedef short short8 __attribute__((ext_vector_type(8)));

static __device__ __forceinline__ unsigned short f2bf(float f) {
  union { float f; unsigned u; } v; v.f = f;
  unsigned r = v.u + 0x7FFF + ((v.u >> 16) & 1);   // RNE
  return (unsigned short)(r >> 16);
}
static __device__ __forceinline__ float bf2f(unsigned short b) {
  union { unsigned u; float f; } v; v.u = ((unsigned)b) << 16;
  return v.f;
}

// ---------------------------------------------------------------------------
// Build K-chunk-major bf16 B: entry (k/8)*COLS + c holds Bt[c][k8..k8+8).
// ---------------------------------------------------------------------------
__global__ __launch_bounds__(256) void build_bt3(
    const float* __restrict__ W, const float* __restrict__ sc,
    const float* __restrict__ dk, unsigned short* __restrict__ Bt3,
    int H, int Kact, int KPAD, int COLS) {
  int i = blockIdx.x * 256 + threadIdx.x;
  if (i >= COLS * KPAD) return;
  int c = i / KPAD;
  int k = i - c * KPAD;
  float v = 0.f;
  if (k < Kact) {
    if (c < H) v = W[(size_t)k * H + c];
    else if (c == H) v = sc[k];
    else if (c == H + 1) v = dk[k];
  }
  Bt3[(size_t)((k >> 3) * COLS + c) * 8 + (k & 7)] = f2bf(v);
}

// ---------------------------------------------------------------------------
// Layer-0 fused MFMA linear, LDS-staged A, HIGH-OCCUPANCY variant:
// RPB=16 rows, 4 waves = 4 K-slices (KSPLIT=4). LDS 16KB stage + 15KB red
// -> 31KB -> 5 blocks/CU (~62% occ). R12 A/B: coalesced staging at 24% occ
// was neutral; this tests staging + occupancy together.
// ---------------------------------------------------------------------------
template <int CFRAGS, int OUTFRAGS, int COLS>
__global__ __launch_bounds__(256) void mfma_linear_l0(
    const float* __restrict__ A, const unsigned short* __restrict__ Bt3,
    const float* __restrict__ sb, const float* __restrict__ db,
    unsigned short* __restrict__ outW, float* __restrict__ s,
    float* __restrict__ Dk, int N, int Kact) {
  constexpr int KPAD = 512;
  constexpr int KSPLIT = 4, RPB = 16;
  constexpr int KS_PER = (KPAD / 32) / KSPLIT;     // 4
  constexpr int H = OUTFRAGS * 16;
  __shared__ unsigned short Ald[RPB * KPAD];                  // 16 KB
  __shared__ float red[(KSPLIT - 1) * 64 * CFRAGS * 4];       // 15 KB

  const int t = threadIdx.x;
  const int rowBase = blockIdx.x * RPB;

  // stage A: 8 iters, 256 thr x f32x4, lane-consecutive (coalesced), then
  // bf16 + XOR swizzle (byte ^= (row&7)<<4) for conflict-free ds_read_b128.
#pragma unroll
  for (int it = 0; it < (RPB * KPAD) / (256 * 4); ++it) {
    int li = it * 1024 + t * 4;
    int row = li >> 9;
    int col = li & 511;
    int grow = rowBase + row;
    f32x4 v = (f32x4)0.f;
    if (grow < N && col < Kact)
      v = *(const f32x4*)(A + (size_t)grow * Kact + col);
    short4v b;
#pragma unroll
    for (int j = 0; j < 4; ++j) b[j] = (short)f2bf(v[j]);
    int byte = row * (KPAD * 2) + ((col * 2) ^ ((row & 7) << 4));
    *(short4v*)((char*)Ald + byte) = b;
  }
  __syncthreads();

  const int kslice = t >> 6;          // 0..3
  const int l = t & 63;
  const int kgrp = l >> 4;
  const int lc = l & 15;
  const int lrow = lc;                // local A row
  const int rowD = rowBase + kgrp * 4;

  f32x4 acc[CFRAGS];
#pragma unroll
  for (int i = 0; i < CFRAGS; ++i) acc[i] = (f32x4)0.f;

  const int rbyte = lrow * (KPAD * 2);
  const int rswz = (lrow & 7) << 4;
#pragma unroll
  for (int kk = 0; kk < KS_PER; ++kk) {
    const int ks = kslice * KS_PER + kk;
    short8 av = *(const short8*)((char*)Ald +
                                 (rbyte + ((ks * 64 + kgrp * 16) ^ rswz)));
    const unsigned short* bbase =
        Bt3 + (size_t)((ks * 4 + kgrp) * COLS + lc) * 8;
#pragma unroll
    for (int fc = 0; fc < CFRAGS; ++fc) {
      short8 bv = *(const short8*)(bbase + fc * 128);
      acc[fc] = __builtin_amdgcn_mfma_f32_16x16x32_bf16(av, bv, acc[fc], 0, 0, 0);
    }
  }

  if (kslice > 0) {
    float* dst = red + ((kslice - 1) * 64 + l) * (CFRAGS * 4);
#pragma unroll
    for (int fc = 0; fc < CFRAGS; ++fc)
#pragma unroll
      for (int r = 0; r < 4; ++r) dst[fc * 4 + r] = acc[fc][r];
  }
  __syncthreads();
  if (kslice == 0) {
#pragma unroll
    for (int s2 = 1; s2 < KSPLIT; ++s2) {
      const float* src2 = red + ((s2 - 1) * 64 + l) * (CFRAGS * 4);
#pragma unroll
      for (int fc = 0; fc < CFRAGS; ++fc)
#pragma unroll
        for (int r = 0; r < 4; ++r) acc[fc][r] += src2[fc * 4 + r];
    }
#pragma unroll
    for (int fc = 0; fc < OUTFRAGS; ++fc) {
#pragma unroll
      for (int r = 0; r < 4; ++r) {
        int gr = rowD + r;
        if (gr < N) outW[(size_t)gr * H + fc * 16 + lc] = f2bf(acc[fc][r]);
      }
    }
    if (lc < 2) {
      f32x4 g = acc[CFRAGS - 1];
#pragma unroll
      for (int r = 0; r < 4; ++r) {
        int gr = rowD + r;
        if (gr < N) {
          if (lc == 0) s[gr] = 1.f / (1.f + expf(-(g[r] + sb[0])));
          else Dk[gr] = g[r] + db[0];
        }
      }
    }
  }
}

// ---------------------------------------------------------------------------
// Layer-1 fused MFMA linear (bf16 A, K=64). RPB=32, KSPLIT=2 (R11 struct).
// ---------------------------------------------------------------------------
template <int KPAD, int CFRAGS, int OUTFRAGS, int COLS>
__global__ __launch_bounds__(256) void mfma_linear_bf(
    const unsigned short* __restrict__ Aptr, const unsigned short* __restrict__ Bt3,
    const float* __restrict__ sb, const float* __restrict__ db,
    unsigned short* __restrict__ outW, float* __restrict__ s,
    float* __restrict__ Dk, int N, int Kact) {
  constexpr int H = OUTFRAGS * 16;
  constexpr int KSPLIT = 2, RG = 2, RPB = 32;
  constexpr int KS_PER = (KPAD / 32) / KSPLIT;
  __shared__ float red[(KSPLIT - 1) * RG * 64 * CFRAGS * 4];

  const int w = threadIdx.x >> 6;
  const int rowgrp = w % RG;
  const int kslice = w / RG;
  const int l = threadIdx.x & 63;
  const int kgrp = l >> 4;
  const int lc = l & 15;
  const int rowA = blockIdx.x * RPB + rowgrp * 16 + lc;
  const int rowD = blockIdx.x * RPB + rowgrp * 16 + kgrp * 4;
  const int rowSafe = (rowA < N) ? rowA : 0;

  f32x4 acc[CFRAGS];
#pragma unroll
  for (int i = 0; i < CFRAGS; ++i) acc[i] = (f32x4)0.f;

#pragma unroll
  for (int kk = 0; kk < KS_PER; ++kk) {
    const int ks = kslice * KS_PER + kk;
    const int kb = ks * 32 + kgrp * 8;
    short8 av = *(const short8*)(Aptr + (size_t)rowSafe * Kact + kb);
    const unsigned short* bbase =
        Bt3 + (size_t)((ks * 4 + kgrp) * COLS + lc) * 8;
#pragma unroll
    for (int fc = 0; fc < CFRAGS; ++fc) {
      short8 bv = *(const short8*)(bbase + fc * 128);
      acc[fc] = __builtin_amdgcn_mfma_f32_16x16x32_bf16(av, bv, acc[fc], 0, 0, 0);
    }
  }

  if (kslice > 0) {
    float* dst = red + ((rowgrp)*64 + l) * (CFRAGS * 4);
#pragma unroll
    for (int fc = 0; fc < CFRAGS; ++fc)
#pragma unroll
      for (int r = 0; r < 4; ++r) dst[fc * 4 + r] = acc[fc][r];
  }
  __syncthreads();
  if (kslice == 0) {
    const float* src2 = red + ((rowgrp)*64 + l) * (CFRAGS * 4);
#pragma unroll
    for (int fc = 0; fc < CFRAGS; ++fc)
#pragma unroll
      for (int r = 0; r < 4; ++r) acc[fc][r] += src2[fc * 4 + r];

#pragma unroll
    for (int fc = 0; fc < OUTFRAGS; ++fc) {
#pragma unroll
      for (int r = 0; r < 4; ++r) {
        int gr = rowD + r;
        if (gr < N) outW[(size_t)gr * H + fc * 16 + lc] = f2bf(acc[fc][r]);
      }
    }
    if (lc < 2) {
      f32x4 g = acc[CFRAGS - 1];
#pragma unroll
      for (int r = 0; r < 4; ++r) {
        int gr = rowD + r;
        if (gr < N) {
          if (lc == 0) s[gr] = 1.f / (1.f + expf(-(g[r] + sb[0])));
          else Dk[gr] = g[r] + db[0];
        }
      }
    }
  }
}

// ---------------------------------------------------------------------------
// Tile binning, 256-node tiles (bucket = dst >> 8, nb <= 256), A+K fused.
// No LDS edge staging (reread ei from L2) -> tiny LDS, high occupancy;
// 8192-edge chunks -> avg run 334 B -> write amp ~1.2x (R12: 84 B runs, 3.2x).
// INT atomics only (R5 lesson).
// ---------------------------------------------------------------------------
#define BIN_CHUNK 8192

__global__ __launch_bounds__(512) void bucket_count2(
    const int* __restrict__ eiA, int EA, int* __restrict__ bcntA,
    const int* __restrict__ eiK, int EK, int* __restrict__ bcntK, int nchA) {
  const int* ei;
  int E, chunk;
  int* bcnt;
  if (blockIdx.x < nchA) { ei = eiA; E = EA; bcnt = bcntA; chunk = blockIdx.x; }
  else { ei = eiK; E = EK; bcnt = bcntK; chunk = blockIdx.x - nchA; }
  __shared__ int lc[256];
  if (threadIdx.x < 256) lc[threadIdx.x] = 0;
  __syncthreads();
  const int base = chunk * BIN_CHUNK;
  for (int k = threadIdx.x; k < BIN_CHUNK; k += 512) {
    int e = base + k;
    if (e < E) atomicAdd(&lc[ei[E + e] >> 8], 1);
  }
  __syncthreads();
  if (threadIdx.x < 256 && lc[threadIdx.x])
    atomicAdd(&bcnt[threadIdx.x], lc[threadIdx.x]);
}

// 2 blocks: block 0 scans A counts, block 1 scans K counts.
__global__ __launch_bounds__(512) void bucket_scan2(
    int* __restrict__ bcntA, int* __restrict__ boffA, int* __restrict__ gcurA,
    int* __restrict__ bcntK, int* __restrict__ boffK, int* __restrict__ gcurK,
    int nb) {
  int* bcnt = blockIdx.x ? bcntK : bcntA;
  int* boff = blockIdx.x ? boffK : boffA;
  int* gcur = blockIdx.x ? gcurK : gcurA;
  __shared__ int sh[512];
  int t = threadIdx.x;
  int v = (t < nb) ? bcnt[t] : 0;
  sh[t] = v;
  __syncthreads();
  int acc = v;
  for (int off = 1; off < 512; off <<= 1) {
    int xx = (t >= off) ? sh[t - off] : 0;
    __syncthreads();
    acc += xx;
    sh[t] = acc;
    __syncthreads();
  }
  if (t < nb) {
    boff[t] = acc - v;
    gcur[t] = acc - v;
  }
  if (t == nb - 1) boff[nb] = acc;
}

// Record: {x = (dst&255)<<16 | src  (src < 65536), y = fp32 weight bits}
__global__ __launch_bounds__(512) void bin_fill2(
    const int* __restrict__ eiA, const float* __restrict__ ewA, int EA,
    int* __restrict__ gcurA, int2* __restrict__ recA,
    const int* __restrict__ eiK, const float* __restrict__ ewK, int EK,
    int* __restrict__ gcurK, int2* __restrict__ recK, int nchA) {
  const int* ei;
  const float* ew;
  int E, chunk;
  int* gcur;
  int2* rec;
  if (blockIdx.x < nchA) {
    ei = eiA; ew = ewA; E = EA; gcur = gcurA; rec = recA; chunk = blockIdx.x;
  } else {
    ei = eiK; ew = ewK; E = EK; gcur = gcurK; rec = recK;
    chunk = blockIdx.x - nchA;
  }
  __shared__ int scnt[256];
  __shared__ int scur[256];
  if (threadIdx.x < 256) scnt[threadIdx.x] = 0;
  __syncthreads();
  const int base = chunk * BIN_CHUNK;
  for (int k = threadIdx.x; k < BIN_CHUNK; k += 512) {
    int e = base + k;
    if (e < E) atomicAdd(&scnt[ei[E + e] >> 8], 1);
  }
  __syncthreads();
  if (threadIdx.x < 256 && scnt[threadIdx.x])
    scur[threadIdx.x] = atomicAdd(&gcur[threadIdx.x], scnt[threadIdx.x]);
  __syncthreads();
  for (int k = threadIdx.x; k < BIN_CHUNK; k += 512) {
    int e = base + k;
    if (e < E) {
      int src = ei[e];            // re-read (L2-hot); no LDS staging
      int dst = ei[E + e];
      int pos = atomicAdd(&scur[dst >> 8], 1);
      rec[pos] = make_int2(((dst & 255) << 16) | src, __float_as_int(ew[e]));
    }
  }
}

// ---------------------------------------------------------------------------
// tile_sort2: one block per 256-node tile (A tiles then K tiles).
// Exact per-dst CSR within the tile's contiguous span. INT LDS atomics.
// ---------------------------------------------------------------------------
__global__ __launch_bounds__(512) void tile_sort2(
    const int2* __restrict__ recRawA, const int* __restrict__ boffA,
    int2* __restrict__ recSA, int* __restrict__ rpA,
    const int2* __restrict__ recRawK, const int* __restrict__ boffK,
    int2* __restrict__ recSK, int* __restrict__ rpK, int N, int nb) {
  const int2* recRaw;
  const int* boff;
  int2* recS;
  int* rp;
  int tile;
  if (blockIdx.x < nb) {
    recRaw = recRawA; boff = boffA; recS = recSA; rp = rpA; tile = blockIdx.x;
  } else {
    recRaw = recRawK; boff = boffK; recS = recSK; rp = rpK;
    tile = blockIdx.x - nb;
  }
  __shared__ int cnt[256];
  __shared__ int sc[256];
  __shared__ int cur[256];
  const int lo = boff[tile], hi = boff[tile + 1];
  const int t = threadIdx.x;
  if (t < 256) cnt[t] = 0;
  __syncthreads();
  for (int j = lo + t; j < hi; j += 512)
    atomicAdd(&cnt[recRaw[j].x >> 16], 1);
  __syncthreads();
  if (t < 256) sc[t] = cnt[t];
  __syncthreads();
  for (int off = 1; off < 256; off <<= 1) {
    int v = 0;
    if (t < 256 && t >= off) v = sc[t - off];
    __syncthreads();
    if (t < 256) sc[t] += v;
    __syncthreads();
  }
  if (t < 256) {
    int excl = sc[t] - cnt[t];
    cur[t] = excl;
    int n = tile * 256 + t;
    if (n < N) rp[n] = lo + excl;
  }
  if (tile == nb - 1 && t == 0) rp[N] = hi;
  __syncthreads();
  for (int j = lo + t; j < hi; j += 512) {
    int2 r = recRaw[j];
    int pos = lo + atomicAdd(&cur[r.x >> 16], 1);
    recS[pos] = r;
  }
}

// ---------------------------------------------------------------------------
// Layer-0 gather: one wave per node (64 feature lanes), 16 chains.
// ---------------------------------------------------------------------------
static __device__ __forceinline__ float gather64(
    const int* __restrict__ rp, const int2* __restrict__ rec,
    const unsigned short* __restrict__ feat, int n, int h) {
  int b = rp[n], e = rp[n + 1];
  float a[16];
#pragma unroll
  for (int u = 0; u < 16; ++u) a[u] = 0.f;
  int j = b;
  for (; j + 16 <= e; j += 16) {
#pragma unroll
    for (int u = 0; u < 16; ++u) {
      int2 r = rec[j + u];
      a[u] += __int_as_float(r.y) *
              bf2f(feat[(size_t)(r.x & 0xFFFF) * 64 + h]);
    }
  }
  for (; j + 4 <= e; j += 4) {
#pragma unroll
    for (int u = 0; u < 4; ++u) {
      int2 r = rec[j + u];
      a[u] += __int_as_float(r.y) *
              bf2f(feat[(size_t)(r.x & 0xFFFF) * 64 + h]);
    }
  }
  for (; j < e; ++j) {
    int2 r = rec[j];
    a[0] += __int_as_float(r.y) * bf2f(feat[(size_t)(r.x & 0xFFFF) * 64 + h]);
  }
  float t0 = ((a[0] + a[1]) + (a[2] + a[3])) + ((a[4] + a[5]) + (a[6] + a[7]));
  float t1 = ((a[8] + a[9]) + (a[10] + a[11])) +
             ((a[12] + a[13]) + (a[14] + a[15]));
  return t0 + t1;
}

__global__ __launch_bounds__(256) void agg_combine64(
    const int* __restrict__ rpA, const int2* __restrict__ recA,
    const int* __restrict__ rpK, const int2* __restrict__ recK,
    const unsigned short* __restrict__ feat, const float* __restrict__ s,
    const float* __restrict__ Dk, unsigned short* __restrict__ outp, int N) {
  int n = __builtin_amdgcn_readfirstlane((blockIdx.x * 256 + threadIdx.x) >> 6);
  if (n >= N) return;
  int h = threadIdx.x & 63;
  float aA = gather64(rpA, recA, feat, n, h);
  float aK = gather64(rpK, recK, feat, n, h);
  float sv = s[n];
  float res = sv * aA + (1.f - sv) * aK +
              GAMMA * Dk[n] * bf2f(feat[(size_t)n * 64 + h]);
  outp[(size_t)n * 64 + h] = f2bf(res);
}

// ---------------------------------------------------------------------------
// Layer-1 gather (H=16, 4 nodes per wave): vector loads, 8 chains.
// ---------------------------------------------------------------------------
static __device__ __forceinline__ float gather16(
    const int* __restrict__ rp, const int2* __restrict__ rec,
    const unsigned short* __restrict__ feat, int n, int h) {
  int b = rp[n], e = rp[n + 1];
  float a0 = 0.f, a1 = 0.f, a2 = 0.f, a3 = 0.f;
  float a4 = 0.f, a5 = 0.f, a6 = 0.f, a7 = 0.f;
  const long long* recq = (const long long*)rec;
  int j = b;
  for (; j + 8 <= e; j += 8) {
    long long q0 = __builtin_nontemporal_load(recq + j + 0);
    long long q1 = __builtin_nontemporal_load(recq + j + 1);
    long long q2 = __builtin_nontemporal_load(recq + j + 2);
    long long q3 = __builtin_nontemporal_load(recq + j + 3);
    long long q4 = __builtin_nontemporal_load(recq + j + 4);
    long long q5 = __builtin_nontemporal_load(recq + j + 5);
    long long q6 = __builtin_nontemporal_load(recq + j + 6);
    long long q7 = __builtin_nontemporal_load(recq + j + 7);
    a0 += __int_as_float((int)(q0 >> 32)) *
          bf2f(feat[(size_t)(q0 & 0xFFFF) * 16 + h]);
    a1 += __int_as_float((int)(q1 >> 32)) *
          bf2f(feat[(size_t)(q1 & 0xFFFF) * 16 + h]);
    a2 += __int_as_float((int)(q2 >> 32)) *
          bf2f(feat[(size_t)(q2 & 0xFFFF) * 16 + h]);
    a3 += __int_as_float((int)(q3 >> 32)) *
          bf2f(feat[(size_t)(q3 & 0xFFFF) * 16 + h]);
    a4 += __int_as_float((int)(q4 >> 32)) *
          bf2f(feat[(size_t)(q4 & 0xFFFF) * 16 + h]);
    a5 += __int_as_float((int)(q5 >> 32)) *
          bf2f(feat[(size_t)(q5 & 0xFFFF) * 16 + h]);
    a6 += __int_as_float((int)(q6 >> 32)) *
          bf2f(feat[(size_t)(q6 & 0xFFFF) * 16 + h]);
    a7 += __int_as_float((int)(q7 >> 32)) *
          bf2f(feat[(size_t)(q7 & 0xFFFF) * 16 + h]);
  }
  for (; j < e; ++j) {
    long long q = __builtin_nontemporal_load(recq + j);
    a0 += __int_as_float((int)(q >> 32)) *
          bf2f(feat[(size_t)(q & 0xFFFF) * 16 + h]);
  }
  return ((a0 + a1) + (a2 + a3)) + ((a4 + a5) + (a6 + a7));
}

__global__ __launch_bounds__(256) void agg_combine16(
    const int* __restrict__ rpA, const int2* __restrict__ recA,
    const int* __restrict__ rpK, const int2* __restrict__ recK,
    const unsigned short* __restrict__ feat, const float* __restrict__ s,
    const float* __restrict__ Dk, float* __restrict__ outp, int N) {
  int tid = blockIdx.x * 256 + threadIdx.x;
  int n = tid >> 4;
  int h = tid & 15;
  if (n >= N) return;
  float aA = gather16(rpA, recA, feat, n, h);
  float aK = gather16(rpK, recK, feat, n, h);
  float sv = s[n];
  float res = sv * aA + (1.f - sv) * aK +
              GAMMA * Dk[n] * bf2f(feat[(size_t)n * 16 + h]);
  outp[(size_t)n * 16 + h] = res;
}

// ---------------------------------------------------------------------------
extern "C" void kernel_launch(void* const* d_in, const int* in_sizes, int n_in,
                              void* d_out, int out_size, void* d_ws, size_t ws_size,
                              hipStream_t stream) {
  const float* x = (const float*)d_in[0];
  const int* edge_index = (const int*)d_in[1];
  const float* edge_weight = (const float*)d_in[2];
  const int* knn_edge_index = (const int*)d_in[3];
  const float* knn_edge_weight = (const float*)d_in[4];
  const float* W0 = (const float*)d_in[5];
  const float* W1 = (const float*)d_in[6];
  const float* score0 = (const float*)d_in[7];
  const float* sbias0 = (const float*)d_in[8];
  const float* score1 = (const float*)d_in[9];
  const float* sbias1 = (const float*)d_in[10];
  const float* Dk0 = (const float*)d_in[11];
  const float* Dbias0 = (const float*)d_in[12];
  const float* Dk1 = (const float*)d_in[13];
  const float* Dbias1 = (const float*)d_in[14];

  const int F = in_sizes[7];          // 500
  const int N = in_sizes[0] / F;      // 50000 (< 65536: src packed in 16 bits)
  const int E = in_sizes[2];          // 1.6M
  const int Ek = in_sizes[4];         // 1.0M
  (void)n_in; (void)ws_size; (void)out_size;

  const int nb = (N + 255) / 256;     // 196 dst tiles (<= 256)

  // ---- workspace bump allocator (256B-aligned slices) ----
  char* cur = (char*)d_ws;
  auto alloc = [&](size_t bytes) {
    char* p = cur;
    cur += (bytes + 255) & ~(size_t)255;
    return (void*)p;
  };
  float* sbuf = (float*)alloc((size_t)N * 4);
  float* dkbuf = (float*)alloc((size_t)N * 4);
  int* bcnt2 = (int*)alloc((size_t)2 * nb * 4);   // ONE slice: memset covers both
  int* bcntA = bcnt2;
  int* bcntK = bcnt2 + nb;
  int* boffA = (int*)alloc((size_t)(nb + 1) * 4);
  int* boffK = (int*)alloc((size_t)(nb + 1) * 4);
  int* gcurA = (int*)alloc((size_t)nb * 4);
  int* gcurK = (int*)alloc((size_t)nb * 4);
  int* rpA = (int*)alloc((size_t)(N + 1) * 4);
  int* rpK = (int*)alloc((size_t)(N + 1) * 4);
  int2* recA = (int2*)alloc((size_t)E * 8);       // sorted (exact CSR)
  int2* recK = (int2*)alloc((size_t)Ek * 8);
  unsigned short* Bt0 = (unsigned short*)alloc((size_t)80 * 512 * 2);
  unsigned short* Bt1 = (unsigned short*)alloc((size_t)32 * 64 * 2);
  // UNION region: recRaw (dead after tile_sort) overlaps the feature buffers
  // (written only after tile_sort completes; same stream => safe).
  char* uni = (char*)alloc((size_t)(E + Ek) * 8);
  int2* recRawA = (int2*)uni;
  int2* recRawK = recRawA + E;
  unsigned short* xWb = (unsigned short*)uni;              // N*64
  unsigned short* x1b = xWb + (size_t)N * 64;              // N*64
  unsigned short* xW1b = x1b + (size_t)N * 64;             // N*16

  // ---- B transposes (tiny), K-chunk-major ----
  build_bt3<<<(80 * 512 + 255) / 256, 256, 0, stream>>>(W0, score0, Dk0, Bt0,
                                                        64, F, 512, 80);
  build_bt3<<<(32 * 64 + 255) / 256, 256, 0, stream>>>(W1, score1, Dk1, Bt1,
                                                       16, 64, 64, 32);

  // ---- tile binning + exact CSR (A+K fused per stage) ----
  hipMemsetAsync(bcnt2, 0, (size_t)2 * nb * sizeof(int), stream);
  const int nchA = (E + BIN_CHUNK - 1) / BIN_CHUNK;
  const int nchK = (Ek + BIN_CHUNK - 1) / BIN_CHUNK;
  bucket_count2<<<nchA + nchK, 512, 0, stream>>>(edge_index, E, bcntA,
                                                 knn_edge_index, Ek, bcntK,
                                                 nchA);
  bucket_scan2<<<2, 512, 0, stream>>>(bcntA, boffA, gcurA, bcntK, boffK,
                                      gcurK, nb);
  bin_fill2<<<nchA + nchK, 512, 0, stream>>>(edge_index, edge_weight, E,
                                             gcurA, recRawA, knn_edge_index,
                                             knn_edge_weight, Ek, gcurK,
                                             recRawK, nchA);
  tile_sort2<<<2 * nb, 512, 0, stream>>>(recRawA, boffA, recA, rpA, recRawK,
                                         boffK, recK, rpK, N, nb);

  const int gemmBlocksL0 = (N + 15) / 16;         // 16 rows/block (KSPLIT 4)
  const int gemmBlocksL1 = (N + 31) / 32;
  const int agg64Blocks = (int)(((size_t)N * 64 + 255) / 256);
  const int agg16Blocks = (int)(((size_t)N * 16 + 255) / 256);

  // ---- Layer 0: F=500 -> H=64 (+gate+Dk), LDS-staged A, high-occ ----
  mfma_linear_l0<5, 4, 80><<<gemmBlocksL0, 256, 0, stream>>>(
      x, Bt0, sbias0, Dbias0, xWb, sbuf, dkbuf, N, F);
  agg_combine64<<<agg64Blocks, 256, 0, stream>>>(rpA, recA, rpK, recK, xWb,
                                                 sbuf, dkbuf, x1b, N);

  // ---- Layer 1: H=64 -> O=16 (+gate+Dk) ----
  mfma_linear_bf<64, 2, 1, 32><<<gemmBlocksL1, 256, 0, stream>>>(
      x1b, Bt1, sbias1, Dbias1, xW1b, sbuf, dkbuf, N, 64);
  agg_combine16<<<agg16Blocks, 256, 0, stream>>>(rpA, recA, rpK, recK, xW1b,
                                                 sbuf, dkbuf, (float*)d_out, N);
}

// Round 14
// 174.079 us; speedup vs baseline: 1.9615x; 1.1640x over previous
//
#include <hip/hip_runtime.h>
#include <math.h>

#define GAMMA 0.1f

typedef float f32x4 __attribute__((ext_vector_type(4)));
typedef short short4v __attribute__((ext_vector_type(4)));
typedef short short8 __attribute__((ext_vector_type(8)));

static __device__ __forceinline__ unsigned short f2bf(float f) {
  union { float f; unsigned u; } v; v.f = f;
  unsigned r = v.u + 0x7FFF + ((v.u >> 16) & 1);   // RNE
  return (unsigned short)(r >> 16);
}
static __device__ __forceinline__ float bf2f(unsigned short b) {
  union { unsigned u; float f; } v; v.u = ((unsigned)b) << 16;
  return v.f;
}

// ---------------------------------------------------------------------------
// Build K-chunk-major bf16 B: entry (k/8)*COLS + c holds Bt[c][k8..k8+8).
// ---------------------------------------------------------------------------
__global__ __launch_bounds__(256) void build_bt3(
    const float* __restrict__ W, const float* __restrict__ sc,
    const float* __restrict__ dk, unsigned short* __restrict__ Bt3,
    int H, int Kact, int KPAD, int COLS) {
  int i = blockIdx.x * 256 + threadIdx.x;
  if (i >= COLS * KPAD) return;
  int c = i / KPAD;
  int k = i - c * KPAD;
  float v = 0.f;
  if (k < Kact) {
    if (c < H) v = W[(size_t)k * H + c];
    else if (c == H) v = sc[k];
    else if (c == H + 1) v = dk[k];
  }
  Bt3[(size_t)((k >> 3) * COLS + c) * 8 + (k & 7)] = f2bf(v);
}

// tiny zero kernel (replaces hipMemsetAsync: fill dispatch showed ~57us
// fixed cost in-graph for a 1.5KB fill — R13 profile)
__global__ __launch_bounds__(256) void zero_cnt(int* __restrict__ p, int n) {
  int i = blockIdx.x * 256 + threadIdx.x;
  if (i < n) p[i] = 0;
}

// ---------------------------------------------------------------------------
// Layer-0 fused MFMA linear, LDS-staged A, high-occupancy (R13 struct).
// RPB=16 rows, 4 waves = 4 K-slices (KSPLIT=4); 31KB LDS -> 5 blocks/CU.
// ---------------------------------------------------------------------------
template <int CFRAGS, int OUTFRAGS, int COLS>
__global__ __launch_bounds__(256) void mfma_linear_l0(
    const float* __restrict__ A, const unsigned short* __restrict__ Bt3,
    const float* __restrict__ sb, const float* __restrict__ db,
    unsigned short* __restrict__ outW, float* __restrict__ s,
    float* __restrict__ Dk, int N, int Kact) {
  constexpr int KPAD = 512;
  constexpr int KSPLIT = 4, RPB = 16;
  constexpr int KS_PER = (KPAD / 32) / KSPLIT;     // 4
  constexpr int H = OUTFRAGS * 16;
  __shared__ unsigned short Ald[RPB * KPAD];                  // 16 KB
  __shared__ float red[(KSPLIT - 1) * 64 * CFRAGS * 4];       // 15 KB

  const int t = threadIdx.x;
  const int rowBase = blockIdx.x * RPB;

#pragma unroll
  for (int it = 0; it < (RPB * KPAD) / (256 * 4); ++it) {
    int li = it * 1024 + t * 4;
    int row = li >> 9;
    int col = li & 511;
    int grow = rowBase + row;
    f32x4 v = (f32x4)0.f;
    if (grow < N && col < Kact)
      v = *(const f32x4*)(A + (size_t)grow * Kact + col);
    short4v b;
#pragma unroll
    for (int j = 0; j < 4; ++j) b[j] = (short)f2bf(v[j]);
    int byte = row * (KPAD * 2) + ((col * 2) ^ ((row & 7) << 4));
    *(short4v*)((char*)Ald + byte) = b;
  }
  __syncthreads();

  const int kslice = t >> 6;          // 0..3
  const int l = t & 63;
  const int kgrp = l >> 4;
  const int lc = l & 15;
  const int lrow = lc;
  const int rowD = rowBase + kgrp * 4;

  f32x4 acc[CFRAGS];
#pragma unroll
  for (int i = 0; i < CFRAGS; ++i) acc[i] = (f32x4)0.f;

  const int rbyte = lrow * (KPAD * 2);
  const int rswz = (lrow & 7) << 4;
#pragma unroll
  for (int kk = 0; kk < KS_PER; ++kk) {
    const int ks = kslice * KS_PER + kk;
    short8 av = *(const short8*)((char*)Ald +
                                 (rbyte + ((ks * 64 + kgrp * 16) ^ rswz)));
    const unsigned short* bbase =
        Bt3 + (size_t)((ks * 4 + kgrp) * COLS + lc) * 8;
#pragma unroll
    for (int fc = 0; fc < CFRAGS; ++fc) {
      short8 bv = *(const short8*)(bbase + fc * 128);
      acc[fc] = __builtin_amdgcn_mfma_f32_16x16x32_bf16(av, bv, acc[fc], 0, 0, 0);
    }
  }

  if (kslice > 0) {
    float* dst = red + ((kslice - 1) * 64 + l) * (CFRAGS * 4);
#pragma unroll
    for (int fc = 0; fc < CFRAGS; ++fc)
#pragma unroll
      for (int r = 0; r < 4; ++r) dst[fc * 4 + r] = acc[fc][r];
  }
  __syncthreads();
  if (kslice == 0) {
#pragma unroll
    for (int s2 = 1; s2 < KSPLIT; ++s2) {
      const float* src2 = red + ((s2 - 1) * 64 + l) * (CFRAGS * 4);
#pragma unroll
      for (int fc = 0; fc < CFRAGS; ++fc)
#pragma unroll
        for (int r = 0; r < 4; ++r) acc[fc][r] += src2[fc * 4 + r];
    }
#pragma unroll
    for (int fc = 0; fc < OUTFRAGS; ++fc) {
#pragma unroll
      for (int r = 0; r < 4; ++r) {
        int gr = rowD + r;
        if (gr < N) outW[(size_t)gr * H + fc * 16 + lc] = f2bf(acc[fc][r]);
      }
    }
    if (lc < 2) {
      f32x4 g = acc[CFRAGS - 1];
#pragma unroll
      for (int r = 0; r < 4; ++r) {
        int gr = rowD + r;
        if (gr < N) {
          if (lc == 0) s[gr] = 1.f / (1.f + expf(-(g[r] + sb[0])));
          else Dk[gr] = g[r] + db[0];
        }
      }
    }
  }
}

// ---------------------------------------------------------------------------
// Layer-1 fused MFMA linear (bf16 A, K=64). RPB=32, KSPLIT=2.
// ---------------------------------------------------------------------------
template <int KPAD, int CFRAGS, int OUTFRAGS, int COLS>
__global__ __launch_bounds__(256) void mfma_linear_bf(
    const unsigned short* __restrict__ Aptr, const unsigned short* __restrict__ Bt3,
    const float* __restrict__ sb, const float* __restrict__ db,
    unsigned short* __restrict__ outW, float* __restrict__ s,
    float* __restrict__ Dk, int N, int Kact) {
  constexpr int H = OUTFRAGS * 16;
  constexpr int KSPLIT = 2, RG = 2, RPB = 32;
  constexpr int KS_PER = (KPAD / 32) / KSPLIT;
  __shared__ float red[(KSPLIT - 1) * RG * 64 * CFRAGS * 4];

  const int w = threadIdx.x >> 6;
  const int rowgrp = w % RG;
  const int kslice = w / RG;
  const int l = threadIdx.x & 63;
  const int kgrp = l >> 4;
  const int lc = l & 15;
  const int rowA = blockIdx.x * RPB + rowgrp * 16 + lc;
  const int rowD = blockIdx.x * RPB + rowgrp * 16 + kgrp * 4;
  const int rowSafe = (rowA < N) ? rowA : 0;

  f32x4 acc[CFRAGS];
#pragma unroll
  for (int i = 0; i < CFRAGS; ++i) acc[i] = (f32x4)0.f;

#pragma unroll
  for (int kk = 0; kk < KS_PER; ++kk) {
    const int ks = kslice * KS_PER + kk;
    const int kb = ks * 32 + kgrp * 8;
    short8 av = *(const short8*)(Aptr + (size_t)rowSafe * Kact + kb);
    const unsigned short* bbase =
        Bt3 + (size_t)((ks * 4 + kgrp) * COLS + lc) * 8;
#pragma unroll
    for (int fc = 0; fc < CFRAGS; ++fc) {
      short8 bv = *(const short8*)(bbase + fc * 128);
      acc[fc] = __builtin_amdgcn_mfma_f32_16x16x32_bf16(av, bv, acc[fc], 0, 0, 0);
    }
  }

  if (kslice > 0) {
    float* dst = red + ((rowgrp)*64 + l) * (CFRAGS * 4);
#pragma unroll
    for (int fc = 0; fc < CFRAGS; ++fc)
#pragma unroll
      for (int r = 0; r < 4; ++r) dst[fc * 4 + r] = acc[fc][r];
  }
  __syncthreads();
  if (kslice == 0) {
    const float* src2 = red + ((rowgrp)*64 + l) * (CFRAGS * 4);
#pragma unroll
    for (int fc = 0; fc < CFRAGS; ++fc)
#pragma unroll
      for (int r = 0; r < 4; ++r) acc[fc][r] += src2[fc * 4 + r];

#pragma unroll
    for (int fc = 0; fc < OUTFRAGS; ++fc) {
#pragma unroll
      for (int r = 0; r < 4; ++r) {
        int gr = rowD + r;
        if (gr < N) outW[(size_t)gr * H + fc * 16 + lc] = f2bf(acc[fc][r]);
      }
    }
    if (lc < 2) {
      f32x4 g = acc[CFRAGS - 1];
#pragma unroll
      for (int r = 0; r < 4; ++r) {
        int gr = rowD + r;
        if (gr < N) {
          if (lc == 0) s[gr] = 1.f / (1.f + expf(-(g[r] + sb[0])));
          else Dk[gr] = g[r] + db[0];
        }
      }
    }
  }
}

// ---------------------------------------------------------------------------
// Tile binning, 256-node tiles (bucket = dst >> 8, nb <= 256), A+K fused.
// INT atomics only (R5 lesson). No LDS edge staging (R13 struct).
// ---------------------------------------------------------------------------
#define BIN_CHUNK 8192

__global__ __launch_bounds__(512) void bucket_count2(
    const int* __restrict__ eiA, int EA, int* __restrict__ bcntA,
    const int* __restrict__ eiK, int EK, int* __restrict__ bcntK, int nchA) {
  const int* ei;
  int E, chunk;
  int* bcnt;
  if (blockIdx.x < nchA) { ei = eiA; E = EA; bcnt = bcntA; chunk = blockIdx.x; }
  else { ei = eiK; E = EK; bcnt = bcntK; chunk = blockIdx.x - nchA; }
  __shared__ int lc[256];
  if (threadIdx.x < 256) lc[threadIdx.x] = 0;
  __syncthreads();
  const int base = chunk * BIN_CHUNK;
  for (int k = threadIdx.x; k < BIN_CHUNK; k += 512) {
    int e = base + k;
    if (e < E) atomicAdd(&lc[ei[E + e] >> 8], 1);
  }
  __syncthreads();
  if (threadIdx.x < 256 && lc[threadIdx.x])
    atomicAdd(&bcnt[threadIdx.x], lc[threadIdx.x]);
}

__global__ __launch_bounds__(512) void bucket_scan2(
    int* __restrict__ bcntA, int* __restrict__ boffA, int* __restrict__ gcurA,
    int* __restrict__ bcntK, int* __restrict__ boffK, int* __restrict__ gcurK,
    int nb) {
  int* bcnt = blockIdx.x ? bcntK : bcntA;
  int* boff = blockIdx.x ? boffK : boffA;
  int* gcur = blockIdx.x ? gcurK : gcurA;
  __shared__ int sh[512];
  int t = threadIdx.x;
  int v = (t < nb) ? bcnt[t] : 0;
  sh[t] = v;
  __syncthreads();
  int acc = v;
  for (int off = 1; off < 512; off <<= 1) {
    int xx = (t >= off) ? sh[t - off] : 0;
    __syncthreads();
    acc += xx;
    sh[t] = acc;
    __syncthreads();
  }
  if (t < nb) {
    boff[t] = acc - v;
    gcur[t] = acc - v;
  }
  if (t == nb - 1) boff[nb] = acc;
}

// Raw record: {x = (dst&255)<<16 | src, y = fp32 weight bits}
__global__ __launch_bounds__(512) void bin_fill2(
    const int* __restrict__ eiA, const float* __restrict__ ewA, int EA,
    int* __restrict__ gcurA, int2* __restrict__ recA,
    const int* __restrict__ eiK, const float* __restrict__ ewK, int EK,
    int* __restrict__ gcurK, int2* __restrict__ recK, int nchA) {
  const int* ei;
  const float* ew;
  int E, chunk;
  int* gcur;
  int2* rec;
  if (blockIdx.x < nchA) {
    ei = eiA; ew = ewA; E = EA; gcur = gcurA; rec = recA; chunk = blockIdx.x;
  } else {
    ei = eiK; ew = ewK; E = EK; gcur = gcurK; rec = recK;
    chunk = blockIdx.x - nchA;
  }
  __shared__ int scnt[256];
  __shared__ int scur[256];
  if (threadIdx.x < 256) scnt[threadIdx.x] = 0;
  __syncthreads();
  const int base = chunk * BIN_CHUNK;
  for (int k = threadIdx.x; k < BIN_CHUNK; k += 512) {
    int e = base + k;
    if (e < E) atomicAdd(&scnt[ei[E + e] >> 8], 1);
  }
  __syncthreads();
  if (threadIdx.x < 256 && scnt[threadIdx.x])
    scur[threadIdx.x] = atomicAdd(&gcur[threadIdx.x], scnt[threadIdx.x]);
  __syncthreads();
  for (int k = threadIdx.x; k < BIN_CHUNK; k += 512) {
    int e = base + k;
    if (e < E) {
      int src = ei[e];
      int dst = ei[E + e];
      int pos = atomicAdd(&scur[dst >> 8], 1);
      rec[pos] = make_int2(((dst & 255) << 16) | src, __float_as_int(ew[e]));
    }
  }
}

// ---------------------------------------------------------------------------
// tile_sort2: one block per 256-node tile (A tiles then K tiles).
// Writes PACKED 4B records: (wbf16 << 16) | src  — dst implied by rp.
// Halves record traffic for both agg passes (R14 change).
// ---------------------------------------------------------------------------
__global__ __launch_bounds__(512) void tile_sort2(
    const int2* __restrict__ recRawA, const int* __restrict__ boffA,
    unsigned* __restrict__ recSA, int* __restrict__ rpA,
    const int2* __restrict__ recRawK, const int* __restrict__ boffK,
    unsigned* __restrict__ recSK, int* __restrict__ rpK, int N, int nb) {
  const int2* recRaw;
  const int* boff;
  unsigned* recS;
  int* rp;
  int tile;
  if (blockIdx.x < nb) {
    recRaw = recRawA; boff = boffA; recS = recSA; rp = rpA; tile = blockIdx.x;
  } else {
    recRaw = recRawK; boff = boffK; recS = recSK; rp = rpK;
    tile = blockIdx.x - nb;
  }
  __shared__ int cnt[256];
  __shared__ int sc[256];
  __shared__ int cur[256];
  const int lo = boff[tile], hi = boff[tile + 1];
  const int t = threadIdx.x;
  if (t < 256) cnt[t] = 0;
  __syncthreads();
  for (int j = lo + t; j < hi; j += 512)
    atomicAdd(&cnt[recRaw[j].x >> 16], 1);
  __syncthreads();
  if (t < 256) sc[t] = cnt[t];
  __syncthreads();
  for (int off = 1; off < 256; off <<= 1) {
    int v = 0;
    if (t < 256 && t >= off) v = sc[t - off];
    __syncthreads();
    if (t < 256) sc[t] += v;
    __syncthreads();
  }
  if (t < 256) {
    int excl = sc[t] - cnt[t];
    cur[t] = excl;
    int n = tile * 256 + t;
    if (n < N) rp[n] = lo + excl;
  }
  if (tile == nb - 1 && t == 0) rp[N] = hi;
  __syncthreads();
  for (int j = lo + t; j < hi; j += 512) {
    int2 r = recRaw[j];
    int pos = lo + atomicAdd(&cur[r.x >> 16], 1);
    recS[pos] = ((unsigned)f2bf(__int_as_float(r.y)) << 16) |
                (unsigned)(r.x & 0xFFFF);
  }
}

// ---------------------------------------------------------------------------
// Layer-0 gather: one wave per node (64 feature lanes), 16 chains.
// 4B records: src = lo 16 bits, weight = bf16 in hi 16 bits.
// ---------------------------------------------------------------------------
static __device__ __forceinline__ float gather64(
    const int* __restrict__ rp, const unsigned* __restrict__ rec,
    const unsigned short* __restrict__ feat, int n, int h) {
  int b = rp[n], e = rp[n + 1];
  float a[16];
#pragma unroll
  for (int u = 0; u < 16; ++u) a[u] = 0.f;
  int j = b;
  for (; j + 16 <= e; j += 16) {
#pragma unroll
    for (int u = 0; u < 16; ++u) {
      unsigned r = rec[j + u];
      a[u] += bf2f((unsigned short)(r >> 16)) *
              bf2f(feat[(size_t)(r & 0xFFFF) * 64 + h]);
    }
  }
  for (; j + 4 <= e; j += 4) {
#pragma unroll
    for (int u = 0; u < 4; ++u) {
      unsigned r = rec[j + u];
      a[u] += bf2f((unsigned short)(r >> 16)) *
              bf2f(feat[(size_t)(r & 0xFFFF) * 64 + h]);
    }
  }
  for (; j < e; ++j) {
    unsigned r = rec[j];
    a[0] += bf2f((unsigned short)(r >> 16)) *
            bf2f(feat[(size_t)(r & 0xFFFF) * 64 + h]);
  }
  float t0 = ((a[0] + a[1]) + (a[2] + a[3])) + ((a[4] + a[5]) + (a[6] + a[7]));
  float t1 = ((a[8] + a[9]) + (a[10] + a[11])) +
             ((a[12] + a[13]) + (a[14] + a[15]));
  return t0 + t1;
}

__global__ __launch_bounds__(256) void agg_combine64(
    const int* __restrict__ rpA, const unsigned* __restrict__ recA,
    const int* __restrict__ rpK, const unsigned* __restrict__ recK,
    const unsigned short* __restrict__ feat, const float* __restrict__ s,
    const float* __restrict__ Dk, unsigned short* __restrict__ outp, int N) {
  int n = __builtin_amdgcn_readfirstlane((blockIdx.x * 256 + threadIdx.x) >> 6);
  if (n >= N) return;
  int h = threadIdx.x & 63;
  float aA = gather64(rpA, recA, feat, n, h);
  float aK = gather64(rpK, recK, feat, n, h);
  float sv = s[n];
  float res = sv * aA + (1.f - sv) * aK +
              GAMMA * Dk[n] * bf2f(feat[(size_t)n * 64 + h]);
  outp[(size_t)n * 64 + h] = f2bf(res);
}

// ---------------------------------------------------------------------------
// Layer-1 gather (H=16, 4 nodes per wave): 4B records, 8 chains.
// ---------------------------------------------------------------------------
static __device__ __forceinline__ float gather16(
    const int* __restrict__ rp, const unsigned* __restrict__ rec,
    const unsigned short* __restrict__ feat, int n, int h) {
  int b = rp[n], e = rp[n + 1];
  float a0 = 0.f, a1 = 0.f, a2 = 0.f, a3 = 0.f;
  float a4 = 0.f, a5 = 0.f, a6 = 0.f, a7 = 0.f;
  int j = b;
  for (; j + 8 <= e; j += 8) {
    unsigned q0 = rec[j + 0];
    unsigned q1 = rec[j + 1];
    unsigned q2 = rec[j + 2];
    unsigned q3 = rec[j + 3];
    unsigned q4 = rec[j + 4];
    unsigned q5 = rec[j + 5];
    unsigned q6 = rec[j + 6];
    unsigned q7 = rec[j + 7];
    a0 += bf2f((unsigned short)(q0 >> 16)) *
          bf2f(feat[(size_t)(q0 & 0xFFFF) * 16 + h]);
    a1 += bf2f((unsigned short)(q1 >> 16)) *
          bf2f(feat[(size_t)(q1 & 0xFFFF) * 16 + h]);
    a2 += bf2f((unsigned short)(q2 >> 16)) *
          bf2f(feat[(size_t)(q2 & 0xFFFF) * 16 + h]);
    a3 += bf2f((unsigned short)(q3 >> 16)) *
          bf2f(feat[(size_t)(q3 & 0xFFFF) * 16 + h]);
    a4 += bf2f((unsigned short)(q4 >> 16)) *
          bf2f(feat[(size_t)(q4 & 0xFFFF) * 16 + h]);
    a5 += bf2f((unsigned short)(q5 >> 16)) *
          bf2f(feat[(size_t)(q5 & 0xFFFF) * 16 + h]);
    a6 += bf2f((unsigned short)(q6 >> 16)) *
          bf2f(feat[(size_t)(q6 & 0xFFFF) * 16 + h]);
    a7 += bf2f((unsigned short)(q7 >> 16)) *
          bf2f(feat[(size_t)(q7 & 0xFFFF) * 16 + h]);
  }
  for (; j < e; ++j) {
    unsigned q = rec[j];
    a0 += bf2f((unsigned short)(q >> 16)) *
          bf2f(feat[(size_t)(q & 0xFFFF) * 16 + h]);
  }
  return ((a0 + a1) + (a2 + a3)) + ((a4 + a5) + (a6 + a7));
}

__global__ __launch_bounds__(256) void agg_combine16(
    const int* __restrict__ rpA, const unsigned* __restrict__ recA,
    const int* __restrict__ rpK, const unsigned* __restrict__ recK,
    const unsigned short* __restrict__ feat, const float* __restrict__ s,
    const float* __restrict__ Dk, float* __restrict__ outp, int N) {
  int tid = blockIdx.x * 256 + threadIdx.x;
  int n = tid >> 4;
  int h = tid & 15;
  if (n >= N) return;
  float aA = gather16(rpA, recA, feat, n, h);
  float aK = gather16(rpK, recK, feat, n, h);
  float sv = s[n];
  float res = sv * aA + (1.f - sv) * aK +
              GAMMA * Dk[n] * bf2f(feat[(size_t)n * 16 + h]);
  outp[(size_t)n * 16 + h] = res;
}

// ---------------------------------------------------------------------------
extern "C" void kernel_launch(void* const* d_in, const int* in_sizes, int n_in,
                              void* d_out, int out_size, void* d_ws, size_t ws_size,
                              hipStream_t stream) {
  const float* x = (const float*)d_in[0];
  const int* edge_index = (const int*)d_in[1];
  const float* edge_weight = (const float*)d_in[2];
  const int* knn_edge_index = (const int*)d_in[3];
  const float* knn_edge_weight = (const float*)d_in[4];
  const float* W0 = (const float*)d_in[5];
  const float* W1 = (const float*)d_in[6];
  const float* score0 = (const float*)d_in[7];
  const float* sbias0 = (const float*)d_in[8];
  const float* score1 = (const float*)d_in[9];
  const float* sbias1 = (const float*)d_in[10];
  const float* Dk0 = (const float*)d_in[11];
  const float* Dbias0 = (const float*)d_in[12];
  const float* Dk1 = (const float*)d_in[13];
  const float* Dbias1 = (const float*)d_in[14];

  const int F = in_sizes[7];          // 500
  const int N = in_sizes[0] / F;      // 50000 (< 65536: src packed in 16 bits)
  const int E = in_sizes[2];          // 1.6M
  const int Ek = in_sizes[4];         // 1.0M
  (void)n_in; (void)ws_size; (void)out_size;

  const int nb = (N + 255) / 256;     // 196 dst tiles (<= 256)

  // ---- workspace bump allocator (256B-aligned slices) ----
  char* cur = (char*)d_ws;
  auto alloc = [&](size_t bytes) {
    char* p = cur;
    cur += (bytes + 255) & ~(size_t)255;
    return (void*)p;
  };
  float* sbuf = (float*)alloc((size_t)N * 4);
  float* dkbuf = (float*)alloc((size_t)N * 4);
  int* bcnt2 = (int*)alloc((size_t)2 * nb * 4);   // ONE slice (R2 lesson)
  int* bcntA = bcnt2;
  int* bcntK = bcnt2 + nb;
  int* boffA = (int*)alloc((size_t)(nb + 1) * 4);
  int* boffK = (int*)alloc((size_t)(nb + 1) * 4);
  int* gcurA = (int*)alloc((size_t)nb * 4);
  int* gcurK = (int*)alloc((size_t)nb * 4);
  int* rpA = (int*)alloc((size_t)(N + 1) * 4);
  int* rpK = (int*)alloc((size_t)(N + 1) * 4);
  unsigned* recA = (unsigned*)alloc((size_t)E * 4);   // sorted, PACKED 4B
  unsigned* recK = (unsigned*)alloc((size_t)Ek * 4);
  unsigned short* Bt0 = (unsigned short*)alloc((size_t)80 * 512 * 2);
  unsigned short* Bt1 = (unsigned short*)alloc((size_t)32 * 64 * 2);
  // UNION region: recRaw (dead after tile_sort) overlaps the feature buffers
  // (written only after tile_sort completes; same stream => safe).
  char* uni = (char*)alloc((size_t)(E + Ek) * 8);
  int2* recRawA = (int2*)uni;
  int2* recRawK = recRawA + E;
  unsigned short* xWb = (unsigned short*)uni;              // N*64
  unsigned short* x1b = xWb + (size_t)N * 64;              // N*64
  unsigned short* xW1b = x1b + (size_t)N * 64;             // N*16

  // ---- B transposes (tiny), K-chunk-major ----
  build_bt3<<<(80 * 512 + 255) / 256, 256, 0, stream>>>(W0, score0, Dk0, Bt0,
                                                        64, F, 512, 80);
  build_bt3<<<(32 * 64 + 255) / 256, 256, 0, stream>>>(W1, score1, Dk1, Bt1,
                                                       16, 64, 64, 32);

  // ---- tile binning + exact CSR (A+K fused per stage) ----
  zero_cnt<<<(2 * nb + 255) / 256, 256, 0, stream>>>(bcnt2, 2 * nb);
  const int nchA = (E + BIN_CHUNK - 1) / BIN_CHUNK;
  const int nchK = (Ek + BIN_CHUNK - 1) / BIN_CHUNK;
  bucket_count2<<<nchA + nchK, 512, 0, stream>>>(edge_index, E, bcntA,
                                                 knn_edge_index, Ek, bcntK,
                                                 nchA);
  bucket_scan2<<<2, 512, 0, stream>>>(bcntA, boffA, gcurA, bcntK, boffK,
                                      gcurK, nb);
  bin_fill2<<<nchA + nchK, 512, 0, stream>>>(edge_index, edge_weight, E,
                                             gcurA, recRawA, knn_edge_index,
                                             knn_edge_weight, Ek, gcurK,
                                             recRawK, nchA);
  tile_sort2<<<2 * nb, 512, 0, stream>>>(recRawA, boffA, recA, rpA, recRawK,
                                         boffK, recK, rpK, N, nb);

  const int gemmBlocksL0 = (N + 15) / 16;
  const int gemmBlocksL1 = (N + 31) / 32;
  const int agg64Blocks = (int)(((size_t)N * 64 + 255) / 256);
  const int agg16Blocks = (int)(((size_t)N * 16 + 255) / 256);

  // ---- Layer 0: F=500 -> H=64 (+gate+Dk) ----
  mfma_linear_l0<5, 4, 80><<<gemmBlocksL0, 256, 0, stream>>>(
      x, Bt0, sbias0, Dbias0, xWb, sbuf, dkbuf, N, F);
  agg_combine64<<<agg64Blocks, 256, 0, stream>>>(rpA, recA, rpK, recK, xWb,
                                                 sbuf, dkbuf, x1b, N);

  // ---- Layer 1: H=64 -> O=16 (+gate+Dk) ----
  mfma_linear_bf<64, 2, 1, 32><<<gemmBlocksL1, 256, 0, stream>>>(
      x1b, Bt1, sbias1, Dbias1, xW1b, sbuf, dkbuf, N, 64);
  agg_combine16<<<agg16Blocks, 256, 0, stream>>>(rpA, recA, rpK, recK, xW1b,
                                                 sbuf, dkbuf, (float*)d_out, N);
}